// Round 4
// baseline (413.295 us; speedup 1.0000x reference)
//
#include <hip/hip_runtime.h>
#include <hip/hip_bf16.h>
#include <stdint.h>

// Problem constants
#define B_  64
#define T_  1000
#define DC_ 512
#define DM_ 80
#define DP_ 128
#define DH_ 128
#define DA_ 128
#define DRN 1024
#define G4  4096

typedef __hip_bfloat16 bf16;
typedef unsigned short u16;
typedef unsigned int   u32;

// MFMA fragment types
typedef short bf8_t __attribute__((ext_vector_type(8)));
typedef float f4_t  __attribute__((ext_vector_type(4)));

// out element offsets: x_dec, ctx, w_new, h0n, c0n, h1n, c1n
#define O_XDEC 0
#define O_CTX  163840
#define O_WN   196608
#define O_H0   260608
#define O_C0   326144
#define O_H1   391680
#define O_C1   457216

__device__ __forceinline__ float b2f(bf16 v) { return __bfloat162float(v); }
__device__ __forceinline__ bf16  f2b(float v) { return __float2bfloat16(v); }
__device__ __forceinline__ u16   f2bu(float v) { return __builtin_bit_cast(u16, __float2bfloat16(v)); }

__device__ __forceinline__ float ldv(const float* p, size_t i) { return p[i]; }
__device__ __forceinline__ float ldv(const bf16*  p, size_t i) { return b2f(p[i]); }
__device__ __forceinline__ void  stv(float* p, size_t i, float v) { p[i] = v; }
__device__ __forceinline__ void  stv(bf16*  p, size_t i, float v) { p[i] = f2b(v); }

// load 8 consecutive elems (i must be 8-aligned) as packed bf16 bits
template<typename T>
__device__ __forceinline__ uint4 ld8bf(const T* p, size_t i) {
    if constexpr (sizeof(T) == 2) {
        return *(const uint4*)((const u16*)p + i);
    } else {
        float4 a = *(const float4*)(p + i);
        float4 b = *(const float4*)(p + i + 4);
        uint4 r;
        r.x = (u32)f2bu(a.x) | ((u32)f2bu(a.y) << 16);
        r.y = (u32)f2bu(a.z) | ((u32)f2bu(a.w) << 16);
        r.z = (u32)f2bu(b.x) | ((u32)f2bu(b.y) << 16);
        r.w = (u32)f2bu(b.z) | ((u32)f2bu(b.w) << 16);
        return r;
    }
}
// load 8 consecutive elems as f32
template<typename T>
__device__ __forceinline__ void ld8f(const T* p, size_t i, float* o) {
    if constexpr (sizeof(T) == 2) {
        uint4 u = *(const uint4*)((const u16*)p + i);
        o[0] = __uint_as_float(u.x << 16); o[1] = __uint_as_float(u.x & 0xffff0000u);
        o[2] = __uint_as_float(u.y << 16); o[3] = __uint_as_float(u.y & 0xffff0000u);
        o[4] = __uint_as_float(u.z << 16); o[5] = __uint_as_float(u.z & 0xffff0000u);
        o[6] = __uint_as_float(u.w << 16); o[7] = __uint_as_float(u.w & 0xffff0000u);
    } else {
        float4 a = *(const float4*)(p + i);
        float4 b = *(const float4*)(p + i + 4);
        o[0]=a.x; o[1]=a.y; o[2]=a.z; o[3]=a.w; o[4]=b.x; o[5]=b.y; o[6]=b.z; o[7]=b.w;
    }
}
__device__ __forceinline__ void ld8f_bits(const u16* p, size_t i, float* o) {
    uint4 u = *(const uint4*)(p + i);
    o[0] = __uint_as_float(u.x << 16); o[1] = __uint_as_float(u.x & 0xffff0000u);
    o[2] = __uint_as_float(u.y << 16); o[3] = __uint_as_float(u.y & 0xffff0000u);
    o[4] = __uint_as_float(u.z << 16); o[5] = __uint_as_float(u.z & 0xffff0000u);
    o[6] = __uint_as_float(u.w << 16); o[7] = __uint_as_float(u.w & 0xffff0000u);
}

// ---------------- per-block dtype sniff (proven heuristic; wave-uniform) -----
__device__ __forceinline__ bool sniff_is_f32(const u32* h0raw) {
    int lane = threadIdx.x & 63;
    int c = 0;
    #pragma unroll
    for (int i = 0; i < 4; ++i) {
        u32 e = (h0raw[lane * 4 + i] >> 7) & 0xFF;
        c += (e >= 100 && e <= 126) ? 1 : 0;
    }
    #pragma unroll
    for (int s = 1; s < 64; s <<= 1) c += __shfl_xor(c, s);
    return c < 128;
}

// ---------------- Threefry-2x32 (bit-exact vs JAX — do not touch) ------------
__device__ __forceinline__ u32 rotl32(u32 v, int r) { return (v << r) | (v >> (32 - r)); }
__device__ __forceinline__ void threefry2x32(u32 k0, u32 k1, u32 x0, u32 x1, u32& y0, u32& y1) {
    u32 ks2 = k0 ^ k1 ^ 0x1BD11BDAu;
    x0 += k0; x1 += k1;
#define TF_R(r) { x0 += x1; x1 = rotl32(x1, r); x1 ^= x0; }
    TF_R(13) TF_R(15) TF_R(26) TF_R(6)
    x0 += k1; x1 += ks2 + 1u;
    TF_R(17) TF_R(29) TF_R(16) TF_R(24)
    x0 += ks2; x1 += k0 + 2u;
    TF_R(13) TF_R(15) TF_R(26) TF_R(6)
    x0 += k0; x1 += k1 + 3u;
    TF_R(17) TF_R(29) TF_R(16) TF_R(24)
    x0 += k1; x1 += ks2 + 4u;
    TF_R(13) TF_R(15) TF_R(26) TF_R(6)
    x0 += ks2; x1 += k0 + 5u;
#undef TF_R
    y0 = x0; y1 = x1;
}
__device__ __forceinline__ float dropout_mask(int which, int j) {
    u32 dk0, dk1, b1, b2;
    threefry2x32(0u, 42u, 0u, (u32)which, dk0, dk1);
    threefry2x32(dk0, dk1, 0u, (u32)j, b1, b2);
    u32 bits = b1 ^ b2;
    float u = __uint_as_float((bits >> 9) | 0x3f800000u) - 1.0f;
    return (u < 0.5f) ? 2.0f : 0.0f;
}

// ============== L0: prep = btprep (blocks 0..159) + prenet (160..223) ========
template<typename T>
__device__ void prep_impl(const T* wm, const T* wq, u16* BTwm, u16* BTwq,
                          const T* x, const T* w1, const T* pb1, const T* w2, const T* pb2,
                          u16* Ab0, float* shbuf) {
    int bid = blockIdx.x, tid = threadIdx.x;
    if (bid < 160) {
        int gid = bid * 256 + tid;
        const T* src; u16* dst; int L, kc, at;
        if (gid < 8192) { L = gid & 63; kc = (gid >> 6) & 15; at = gid >> 10; src = wm; dst = BTwm + (size_t)gid * 8; }
        else { int g = gid - 8192; L = g & 63; kc = (g >> 6) & 63; at = g >> 12; src = wq; dst = BTwq + (size_t)g * 8; }
        int col = at * 16 + (L & 15);
        int krow = kc * 32 + (L >> 4) * 8;
        u16 v[8];
        #pragma unroll
        for (int j = 0; j < 8; ++j) v[j] = f2bu(ldv(src, (size_t)(krow + j) * DA_ + col));
        uint4 pk;
        pk.x = v[0] | ((u32)v[1] << 16); pk.y = v[2] | ((u32)v[3] << 16);
        pk.z = v[4] | ((u32)v[5] << 16); pk.w = v[6] | ((u32)v[7] << 16);
        *(uint4*)dst = pk;
    } else {
        int b = bid - 160;
        float* xs = shbuf;            // [80]
        float* hs = shbuf + DM_;      // [128]
        if (tid < DM_) xs[tid] = ldv(x, (size_t)b * DM_ + tid);
        __syncthreads();
        if (tid < DH_) {
            float acc = ldv(pb1, tid);
            #pragma unroll 8
            for (int k = 0; k < DM_; ++k) acc = fmaf(xs[k], ldv(w1, (size_t)k * DH_ + tid), acc);
            acc = fmaxf(acc, 0.f) * dropout_mask(0, b * DH_ + tid);
            hs[tid] = acc;
        }
        __syncthreads();
        if (tid < DP_) {
            float acc2 = ldv(pb2, tid);
            #pragma unroll 8
            for (int k = 0; k < DH_; ++k) acc2 = fmaf(hs[k], ldv(w2, (size_t)k * DP_ + tid), acc2);
            acc2 = fmaxf(acc2, 0.f) * dropout_mask(1, b * DP_ + tid);
            Ab0[(size_t)b * 1664 + tid] = f2bu(acc2);
        }
    }
}
__global__ __launch_bounds__(256) void prep_kernel(const u32* h0r,
        const void* wm, const void* wq, u16* BTwm, u16* BTwq,
        const void* x, const void* w1, const void* pb1, const void* w2, const void* pb2,
        u16* Ab0) {
    __shared__ float shbuf[DM_ + DH_];
    if (sniff_is_f32(h0r))
        prep_impl<float>((const float*)wm, (const float*)wq, BTwm, BTwq, (const float*)x,
                         (const float*)w1, (const float*)pb1, (const float*)w2, (const float*)pb2, Ab0, shbuf);
    else
        prep_impl<bf16>((const bf16*)wm, (const bf16*)wq, BTwm, BTwq, (const bf16*)x,
                        (const bf16*)w1, (const bf16*)pb1, (const bf16*)w2, (const bf16*)pb2, Ab0, shbuf);
}

// ============== L1a: ctx streaming bmm: CTXP[chunk][b][c] ====================
// grid (16 chunks of 64 t, 64 b), 256 thr = 4 waves. Wave wv owns rows
// t0 + wv + 4*i; lane c8 owns cols c8*8..c8*8+7. Every wave-load = one fully
// coalesced 1KB row. No staging, no MFMA — pure stream probe + ctx producer.
template<typename T>
__device__ void ctxs_impl(const T* mem, const T* w, float* CTXP, float* part, float* wsh) {
    int tid = threadIdx.x;
    int chunk = blockIdx.x, b = blockIdx.y;
    int t0 = chunk * 64;
    if (tid < 64) wsh[tid] = (t0 + tid < T_) ? ldv(w, (size_t)b * T_ + t0 + tid) : 0.f;
    __syncthreads();
    int wv = tid >> 6, c8 = tid & 63;
    float acc[8] = {};
    #pragma unroll 4
    for (int i = 0; i < 16; ++i) {
        int r = 4 * i + wv;
        int t = t0 + r;
        if (t < T_) {
            float v[8];
            ld8f(mem, (size_t)(b * T_ + t) * DC_ + c8 * 8, v);
            float wvv = wsh[r];
            #pragma unroll
            for (int j = 0; j < 8; ++j) acc[j] = fmaf(wvv, v[j], acc[j]);
        }
    }
    #pragma unroll
    for (int j = 0; j < 8; ++j) part[wv * 512 + c8 * 8 + j] = acc[j];
    __syncthreads();
    int c = tid * 2;
    float s0 = part[c]     + part[512 + c]     + part[1024 + c]     + part[1536 + c];
    float s1 = part[c + 1] + part[512 + c + 1] + part[1024 + c + 1] + part[1536 + c + 1];
    *(float2*)&CTXP[((size_t)chunk * 64 + b) * DC_ + c] = make_float2(s0, s1);
}
__global__ __launch_bounds__(256) void ctxs_kernel(const u32* h0r,
        const void* mem, const void* w, float* CTXP) {
    __shared__ float part[4 * 512];
    __shared__ float wsh[64];
    if (sniff_is_f32(h0r))
        ctxs_impl<float>((const float*)mem, (const float*)w, CTXP, part, wsh);
    else
        ctxs_impl<bf16>((const bf16*)mem, (const bf16*)w, CTXP, part, wsh);
}

// ============== L1b: Mproj = memory @ wm (LDS-free, reg-direct MFMA) =========
// grid (16 t-tiles of 64, 64 b), 256 thr = 4 waves, NO barriers/LDS.
// A-frag loaded per-lane straight from global: lane (q16,m) reads row
// t0+wv*16+m, cols kc*32+q16*8 — wave = 16 rows x 64B, 64B-coalesced.
// Runs after ctxs so the 65MB re-read is L3-warm.
template<typename T>
__device__ void mproj_impl(const T* mem, const u16* BTwm, u16* Mproj) {
    int tid = threadIdx.x;
    int t0 = blockIdx.x * 64, b = blockIdx.y;
    int wv = tid >> 6, L = tid & 63;
    int m = L & 15, q16 = L >> 4;
    int row = t0 + wv * 16 + m;
    int rl = (row < T_) ? row : (T_ - 1);     // clamp: loads stay in-bounds
    const T* arow = mem + (size_t)(b * T_ + rl) * DC_;
    f4_t acc[8];
    #pragma unroll
    for (int at = 0; at < 8; ++at) acc[at] = (f4_t){0.f, 0.f, 0.f, 0.f};
    #pragma unroll 4
    for (int kc = 0; kc < 16; ++kc) {
        bf8_t af = __builtin_bit_cast(bf8_t, ld8bf(arow, kc * 32 + q16 * 8));
        #pragma unroll
        for (int at = 0; at < 8; ++at) {
            bf8_t bfrag = *(const bf8_t*)(BTwm + ((size_t)(at * 16 + kc) * 64 + L) * 8);
            acc[at] = __builtin_amdgcn_mfma_f32_16x16x32_bf16(af, bfrag, acc[at], 0, 0, 0);
        }
    }
    // Mproj store (bf16): row=wv*16+q16*4+r, col=at*16+m  (proven C/D layout)
    #pragma unroll
    for (int at = 0; at < 8; ++at)
        #pragma unroll
        for (int r = 0; r < 4; ++r) {
            int trow = t0 + wv * 16 + q16 * 4 + r;
            if (trow < T_) Mproj[(size_t)(b * T_ + trow) * DA_ + at * 16 + m] = f2bu(acc[at][r]);
        }
}
__global__ __launch_bounds__(256) void mproj_kernel(const u32* h0r,
        const void* mem, const u16* BTwm, u16* Mproj) {
    if (sniff_is_f32(h0r))
        mproj_impl<float>((const float*)mem, BTwm, Mproj);
    else
        mproj_impl<bf16>((const bf16*)mem, BTwm, Mproj);
}

// ============== L2: pack0 = ctx reduce + A-buffer packing + xdec tail zeros ==
template<typename T>
__device__ void pack0_impl(const float* CTXP, const T* h0p, const T* h1p,
                           u16* Ab0, u16* Ab1, T* out) {
    int b = blockIdx.x, tid = threadIdx.x;
    T* ctxout = out + O_CTX;
    T* xdec = out + O_XDEC;
    for (int c = tid; c < DC_; c += 256) {
        float s = 0.f;
        #pragma unroll
        for (int t = 0; t < 16; ++t) s += CTXP[((size_t)t * 64 + b) * DC_ + c];
        u16 bv = f2bu(s);
        Ab0[(size_t)b * 1664 + 128 + c] = bv;
        Ab1[(size_t)b * 2560 + 1024 + c] = bv;
        stv(ctxout, (size_t)b * DC_ + c, s);
        stv(xdec, (size_t)b * 2560 + 2048 + c, 0.f);
    }
    for (int u = tid; u < DRN; u += 256) {
        Ab0[(size_t)b * 1664 + 640 + u]  = f2bu(ldv(h0p, (size_t)b * DRN + u));
        Ab1[(size_t)b * 2560 + 1536 + u] = f2bu(ldv(h1p, (size_t)b * DRN + u));
    }
}
__global__ __launch_bounds__(256) void pack0_kernel(const u32* h0r, const float* CTXP,
        const void* h0p, const void* h1p, u16* Ab0, u16* Ab1, void* out) {
    if (sniff_is_f32(h0r))
        pack0_impl<float>(CTXP, (const float*)h0p, (const float*)h1p, Ab0, Ab1, (float*)out);
    else
        pack0_impl<bf16>(CTXP, (const bf16*)h0p, (const bf16*)h1p, Ab0, Ab1, (bf16*)out);
}

// ============== L3/L5: LSTM gate GEMM (fp32 SMEM, per-split buffers) =========
template<typename T>
__device__ void gemm_impl(const u16* Abuf, int K, int L12, const T* Wih, const T* Whh,
                          float* Gs, int nchunks, float (*As)[34], float (*Ws)[64]) {
    int tid = threadIdx.x;
    int n0b = blockIdx.x * 64;
    int kbase = blockIdx.y * (nchunks * 32);
    int cx = tid & 15, ry = tid >> 4;
    int b0 = ry * 4, n0 = cx * 4;
    int a_bb = tid >> 2, a_k8 = (tid & 3) * 8;
    int w_k  = tid >> 3, w_n8 = (tid & 7) * 8;
    float acc[4][4] = {};
    for (int ch = 0; ch < nchunks; ++ch) {
        int k0 = kbase + ch * 32;
        __syncthreads();
        {
            float v[8];
            ld8f_bits(Abuf, (size_t)a_bb * K + k0 + a_k8, v);
            #pragma unroll
            for (int j = 0; j < 8; ++j) As[a_bb][a_k8 + j] = v[j];
            int kg = k0 + w_k;
            const T* wr = (kg < L12) ? (Wih + (size_t)kg * G4) : (Whh + (size_t)(kg - L12) * G4);
            ld8f(wr, n0b + w_n8, v);
            #pragma unroll
            for (int j = 0; j < 8; ++j) Ws[w_k][w_n8 + j] = v[j];
        }
        __syncthreads();
        #pragma unroll
        for (int kk = 0; kk < 32; kk += 2) {
            float2 av[4];
            #pragma unroll
            for (int r = 0; r < 4; ++r) av[r] = *(const float2*)&As[b0 + r][kk];
            float4 w0 = *(const float4*)&Ws[kk][n0];
            float4 w1 = *(const float4*)&Ws[kk + 1][n0];
            #pragma unroll
            for (int r = 0; r < 4; ++r) {
                acc[r][0] = fmaf(av[r].x, w0.x, acc[r][0]); acc[r][0] = fmaf(av[r].y, w1.x, acc[r][0]);
                acc[r][1] = fmaf(av[r].x, w0.y, acc[r][1]); acc[r][1] = fmaf(av[r].y, w1.y, acc[r][1]);
                acc[r][2] = fmaf(av[r].x, w0.z, acc[r][2]); acc[r][2] = fmaf(av[r].y, w1.z, acc[r][2]);
                acc[r][3] = fmaf(av[r].x, w0.w, acc[r][3]); acc[r][3] = fmaf(av[r].y, w1.w, acc[r][3]);
            }
        }
    }
    float* outp = Gs + (size_t)blockIdx.y * (64 * G4);
    #pragma unroll
    for (int r = 0; r < 4; ++r)
        *(float4*)&outp[(size_t)(b0 + r) * G4 + n0b + n0] =
            make_float4(acc[r][0], acc[r][1], acc[r][2], acc[r][3]);
}
__global__ __launch_bounds__(256) void gemm_kernel(const u32* h0r, const u16* Abuf,
        int K, int L12, const void* Wih, const void* Whh, float* Gs, int nchunks) {
    __shared__ float As[64][34];
    __shared__ float Ws[32][64];
    if (sniff_is_f32(h0r))
        gemm_impl<float>(Abuf, K, L12, (const float*)Wih, (const float*)Whh, Gs, nchunks, As, Ws);
    else
        gemm_impl<bf16>(Abuf, K, L12, (const bf16*)Wih, (const bf16*)Whh, Gs, nchunks, As, Ws);
}

// ============== L4/L6: split-reduce + gates + zoneout + outputs ==============
template<typename T>
__device__ void gate_impl(const float* Gs, int nsplit, const T* bias, const T* hprev,
                          const T* cprev, T* out, int ho_off, int co_off, int xoff,
                          u16* Hcat, int hoff, u16* Ab1) {
    int idx = blockIdx.x * 256 + threadIdx.x;     // [0, 65536)
    int b = idx >> 10, u = idx & 1023;
    float gi = ldv(bias, u);
    float gf = ldv(bias, 1024 + u);
    float gg = ldv(bias, 2048 + u);
    float go = ldv(bias, 3072 + u);
    for (int s = 0; s < nsplit; ++s) {
        const float* g = Gs + (size_t)s * (64 * G4) + (size_t)b * G4;
        gi += g[u]; gf += g[1024 + u]; gg += g[2048 + u]; go += g[3072 + u];
    }
    float c = ldv(cprev, idx), h = ldv(hprev, idx);
    float si = 1.f / (1.f + expf(-gi));
    float sf = 1.f / (1.f + expf(-gf));
    float so = 1.f / (1.f + expf(-go));
    float cn = sf * c + si * tanhf(gg);
    float hn = so * tanhf(cn);
    float ho = 0.9f * hn + 0.1f * h;
    float co = 0.9f * cn + 0.1f * c;
    stv(out + ho_off, idx, ho);
    stv(out + co_off, idx, co);
    stv(out + O_XDEC, (size_t)b * 2560 + xoff + u, ho);
    u16 hb = f2bu(ho);
    Hcat[(size_t)b * 2048 + hoff + u] = hb;
    if (Ab1 != nullptr) Ab1[(size_t)b * 2560 + u] = hb;
}
__global__ __launch_bounds__(256) void gate_kernel(const u32* h0r, const float* Gs, int nsplit,
        const void* bias, const void* hprev, const void* cprev, void* out,
        int ho_off, int co_off, int xoff, u16* Hcat, int hoff, u16* Ab1) {
    if (sniff_is_f32(h0r))
        gate_impl<float>(Gs, nsplit, (const float*)bias, (const float*)hprev, (const float*)cprev,
                         (float*)out, ho_off, co_off, xoff, Hcat, hoff, Ab1);
    else
        gate_impl<bf16>(Gs, nsplit, (const bf16*)bias, (const bf16*)hprev, (const bf16*)cprev,
                        (bf16*)out, ho_off, co_off, xoff, Hcat, hoff, Ab1);
}

// ============== L7: q GEMM (MFMA, dtype-free): QP[s][64][128] ================
__global__ __launch_bounds__(256) void qgemm_kernel(const u16* Hcat, const u16* BTwq, float* QP) {
    int tid = threadIdx.x;
    int w = tid >> 6, L = tid & 63;
    int m = L & 15, q16 = L >> 4;
    f4_t acc[8];
    #pragma unroll
    for (int at = 0; at < 8; ++at) acc[at] = (f4_t){0.f, 0.f, 0.f, 0.f};
    #pragma unroll
    for (int kcl = 0; kcl < 8; ++kcl) {
        int kc = blockIdx.x * 8 + kcl;
        bf8_t af = *(const bf8_t*)(Hcat + (size_t)(w * 16 + m) * 2048 + kc * 32 + q16 * 8);
        #pragma unroll
        for (int at = 0; at < 8; ++at) {
            bf8_t bfrag = *(const bf8_t*)(BTwq + ((size_t)(at * 64 + kc) * 64 + L) * 8);
            acc[at] = __builtin_amdgcn_mfma_f32_16x16x32_bf16(af, bfrag, acc[at], 0, 0, 0);
        }
    }
    #pragma unroll
    for (int at = 0; at < 8; ++at)
        #pragma unroll
        for (int r = 0; r < 4; ++r)
            QP[((size_t)blockIdx.x * 64 + w * 16 + q16 * 4 + r) * DA_ + at * 16 + m] = acc[at][r];
}

// ============== L8: attention epilogue (tanh-dot-sigmoid) + fused wnew =======
template<typename T>
__device__ void attn_impl(const u16* Mproj, const float* QP, const T* ab, const T* av,
                          const T* w, T* out, float* qa, float* avl, float* psh) {
    int tid = threadIdx.x;
    int t0 = blockIdx.x * 64, b = blockIdx.y;
    T* wout = out + O_WN;
    if (tid < DA_) {
        float s = ldv(ab, tid);
        #pragma unroll
        for (int s8 = 0; s8 < 8; ++s8) s += QP[((size_t)s8 * 64 + b) * DA_ + tid];
        qa[tid] = s;
        avl[tid] = ldv(av, tid);
    }
    __syncthreads();
    int quad = tid & 3, r = tid >> 2;   // 4 threads per row, 32 a each
    #pragma unroll
    for (int rbase = 0; rbase < 2; ++rbase) {
        int rrow = (rbase == 0) ? r : 64;          // row 64 handled by r==0 quads
        bool act = (rbase == 0) || (r == 0);
        int t = t0 - 1 + rrow;
        float e = 0.f;
        if (act && t >= 0 && t < T_) {
            #pragma unroll
            for (int a8 = 0; a8 < 4; ++a8) {
                float v[8];
                ld8f_bits(Mproj, (size_t)(b * T_ + t) * DA_ + quad * 32 + a8 * 8, v);
                #pragma unroll
                for (int j = 0; j < 8; ++j) {
                    int a = quad * 32 + a8 * 8 + j;
                    e = fmaf(avl[a], tanhf(qa[a] + v[j]), e);
                }
            }
        }
        e += __shfl_xor(e, 1);
        e += __shfl_xor(e, 2);
        if (act && quad == 0 && t >= 0 && t < T_) psh[rrow] = 1.f / (1.f + expf(-e));
    }
    __syncthreads();
    if (tid < 64) {
        int t = t0 + tid;
        if (t < T_) {
            float val = ldv(w, (size_t)b * T_ + t) * psh[tid + 1];
            if (t > 0) val = fmaf(ldv(w, (size_t)b * T_ + t - 1), 1.f - psh[tid], val);
            stv(wout, (size_t)b * T_ + t, val);
        }
    }
}
__global__ __launch_bounds__(256) void attn_kernel(const u32* h0r, const u16* Mproj,
        const float* QP, const void* ab, const void* av, const void* w, void* out) {
    __shared__ float qa[DA_];
    __shared__ float avl[DA_];
    __shared__ float psh[66];
    if (sniff_is_f32(h0r))
        attn_impl<float>(Mproj, QP, (const float*)ab, (const float*)av, (const float*)w,
                         (float*)out, qa, avl, psh);
    else
        attn_impl<bf16>(Mproj, QP, (const bf16*)ab, (const bf16*)av, (const bf16*)w,
                        (bf16*)out, qa, avl, psh);
}

// ---------------- launch -----------------------------------------------------
extern "C" void kernel_launch(void* const* d_in, const int* in_sizes, int n_in,
                              void* d_out, int out_size, void* d_ws, size_t ws_size,
                              hipStream_t stream) {
    (void)in_sizes; (void)n_in; (void)out_size; (void)ws_size;

    // workspace layout (f32 units). Total 9,244,672 f32 = 37.0 MiB.
    float* wsf   = (float*)d_ws;
    float* GS    = wsf;                        // 16 x 262144 (per-split gate buffers)
    float* CTXP  = wsf + 4194304;              // 16 x 64 x 512 ctx partials
    float* QP    = wsf + 4718592;              // 8 x 64 x 128 q partials
    u16*   MPROJ = (u16*)(wsf + 4784128);      // 64 x 1000 x 128 bf16
    u16*   AB0   = (u16*)(wsf + 8880128);      // 64 x 1664 bf16
    u16*   AB1   = (u16*)(wsf + 8933376);      // 64 x 2560 bf16
    u16*   HCAT  = (u16*)(wsf + 9015296);      // 64 x 2048 bf16
    u16*   BTWM  = (u16*)(wsf + 9080832);      // 65536 bf16
    u16*   BTWQ  = (u16*)(wsf + 9113600);      // 262144 bf16

    const u32* H0R = (const u32*)d_in[2];

    // L0: B-fragment prep (wm,wq) + prenet -> AB0[:,0:128]
    prep_kernel<<<224, 256, 0, stream>>>(H0R, d_in[19], d_in[18], BTWM, BTWQ,
                                         d_in[0], d_in[8], d_in[9], d_in[10], d_in[11], AB0);
    // L1a: ctx streaming bmm (cold HBM read — pure-stream probe)
    ctxs_kernel<<<dim3(16, 64), 256, 0, stream>>>(H0R, d_in[6], d_in[1], CTXP);
    // L1b: Mproj = memory @ wm (reg-direct MFMA; L3-warm re-read)
    mproj_kernel<<<dim3(16, 64), 256, 0, stream>>>(H0R, d_in[6], BTWM, MPROJ);
    // L2: ctx reduce + A-buffer packing + ctx out + xdec tail zeros
    pack0_kernel<<<64, 256, 0, stream>>>(H0R, CTXP, d_in[2], d_in[4], AB0, AB1, d_out);
    // L3/L4: LSTM layer 0 (K=1664, 13 splits x 4 chunks)
    gemm_kernel<<<dim3(64, 13), 256, 0, stream>>>(H0R, AB0, 1664, 640, d_in[12], d_in[13], GS, 4);
    gate_kernel<<<256, 256, 0, stream>>>(H0R, GS, 13, d_in[14], d_in[2], d_in[3], d_out,
                                         O_H0, O_C0, 0, HCAT, 0, AB1);
    // L5/L6: LSTM layer 1 (K=2560, 16 splits x 5 chunks)
    gemm_kernel<<<dim3(64, 16), 256, 0, stream>>>(H0R, AB1, 2560, 1536, d_in[15], d_in[16], GS, 5);
    gate_kernel<<<256, 256, 0, stream>>>(H0R, GS, 16, d_in[17], d_in[4], d_in[5], d_out,
                                         O_H1, O_C1, 1024, HCAT, 1024, (u16*)nullptr);
    // L7: q = Hcat @ wq (8 k-splits, no atomics)
    qgemm_kernel<<<8, 256, 0, stream>>>(HCAT, BTWQ, QP);
    // L8: p = sigmoid(v . tanh(q + Mproj)) fused with w_new
    attn_kernel<<<dim3(16, 64), 256, 0, stream>>>(H0R, MPROJ, QP, d_in[20], d_in[21], d_in[1], d_out);
}

// Round 5
// 412.316 us; speedup vs baseline: 1.0024x; 1.0024x over previous
//
#include <hip/hip_runtime.h>
#include <hip/hip_bf16.h>
#include <stdint.h>

// Problem constants
#define B_  64
#define T_  1000
#define DC_ 512
#define DM_ 80
#define DP_ 128
#define DH_ 128
#define DA_ 128
#define DRN 1024
#define G4  4096

typedef __hip_bfloat16 bf16;
typedef unsigned short u16;
typedef unsigned int   u32;

// MFMA fragment types
typedef short bf8_t __attribute__((ext_vector_type(8)));
typedef float f4_t  __attribute__((ext_vector_type(4)));

// out element offsets: x_dec, ctx, w_new, h0n, c0n, h1n, c1n
#define O_XDEC 0
#define O_CTX  163840
#define O_WN   196608
#define O_H0   260608
#define O_C0   326144
#define O_H1   391680
#define O_C1   457216

__device__ __forceinline__ float b2f(bf16 v) { return __bfloat162float(v); }
__device__ __forceinline__ bf16  f2b(float v) { return __float2bfloat16(v); }
__device__ __forceinline__ u16   f2bu(float v) { return __builtin_bit_cast(u16, __float2bfloat16(v)); }

__device__ __forceinline__ float ldv(const float* p, size_t i) { return p[i]; }
__device__ __forceinline__ float ldv(const bf16*  p, size_t i) { return b2f(p[i]); }
__device__ __forceinline__ void  stv(float* p, size_t i, float v) { p[i] = v; }
__device__ __forceinline__ void  stv(bf16*  p, size_t i, float v) { p[i] = f2b(v); }

// load 8 consecutive elems (i must be 8-aligned) as packed bf16 bits
template<typename T>
__device__ __forceinline__ uint4 ld8bf(const T* p, size_t i) {
    if constexpr (sizeof(T) == 2) {
        return *(const uint4*)((const u16*)p + i);
    } else {
        float4 a = *(const float4*)(p + i);
        float4 b = *(const float4*)(p + i + 4);
        uint4 r;
        r.x = (u32)f2bu(a.x) | ((u32)f2bu(a.y) << 16);
        r.y = (u32)f2bu(a.z) | ((u32)f2bu(a.w) << 16);
        r.z = (u32)f2bu(b.x) | ((u32)f2bu(b.y) << 16);
        r.w = (u32)f2bu(b.z) | ((u32)f2bu(b.w) << 16);
        return r;
    }
}
// load 8 consecutive elems as f32
template<typename T>
__device__ __forceinline__ void ld8f(const T* p, size_t i, float* o) {
    if constexpr (sizeof(T) == 2) {
        uint4 u = *(const uint4*)((const u16*)p + i);
        o[0] = __uint_as_float(u.x << 16); o[1] = __uint_as_float(u.x & 0xffff0000u);
        o[2] = __uint_as_float(u.y << 16); o[3] = __uint_as_float(u.y & 0xffff0000u);
        o[4] = __uint_as_float(u.z << 16); o[5] = __uint_as_float(u.z & 0xffff0000u);
        o[6] = __uint_as_float(u.w << 16); o[7] = __uint_as_float(u.w & 0xffff0000u);
    } else {
        float4 a = *(const float4*)(p + i);
        float4 b = *(const float4*)(p + i + 4);
        o[0]=a.x; o[1]=a.y; o[2]=a.z; o[3]=a.w; o[4]=b.x; o[5]=b.y; o[6]=b.z; o[7]=b.w;
    }
}
__device__ __forceinline__ void ld8f_bits(const u16* p, size_t i, float* o) {
    uint4 u = *(const uint4*)(p + i);
    o[0] = __uint_as_float(u.x << 16); o[1] = __uint_as_float(u.x & 0xffff0000u);
    o[2] = __uint_as_float(u.y << 16); o[3] = __uint_as_float(u.y & 0xffff0000u);
    o[4] = __uint_as_float(u.z << 16); o[5] = __uint_as_float(u.z & 0xffff0000u);
    o[6] = __uint_as_float(u.w << 16); o[7] = __uint_as_float(u.w & 0xffff0000u);
}

// ---------------- per-block dtype sniff (proven heuristic; wave-uniform) -----
__device__ __forceinline__ bool sniff_is_f32(const u32* h0raw) {
    int lane = threadIdx.x & 63;
    int c = 0;
    #pragma unroll
    for (int i = 0; i < 4; ++i) {
        u32 e = (h0raw[lane * 4 + i] >> 7) & 0xFF;
        c += (e >= 100 && e <= 126) ? 1 : 0;
    }
    #pragma unroll
    for (int s = 1; s < 64; s <<= 1) c += __shfl_xor(c, s);
    return c < 128;
}

// ---------------- Threefry-2x32 (bit-exact vs JAX — do not touch) ------------
__device__ __forceinline__ u32 rotl32(u32 v, int r) { return (v << r) | (v >> (32 - r)); }
__device__ __forceinline__ void threefry2x32(u32 k0, u32 k1, u32 x0, u32 x1, u32& y0, u32& y1) {
    u32 ks2 = k0 ^ k1 ^ 0x1BD11BDAu;
    x0 += k0; x1 += k1;
#define TF_R(r) { x0 += x1; x1 = rotl32(x1, r); x1 ^= x0; }
    TF_R(13) TF_R(15) TF_R(26) TF_R(6)
    x0 += k1; x1 += ks2 + 1u;
    TF_R(17) TF_R(29) TF_R(16) TF_R(24)
    x0 += ks2; x1 += k0 + 2u;
    TF_R(13) TF_R(15) TF_R(26) TF_R(6)
    x0 += k0; x1 += k1 + 3u;
    TF_R(17) TF_R(29) TF_R(16) TF_R(24)
    x0 += k1; x1 += ks2 + 4u;
    TF_R(13) TF_R(15) TF_R(26) TF_R(6)
    x0 += ks2; x1 += k0 + 5u;
#undef TF_R
    y0 = x0; y1 = x1;
}
__device__ __forceinline__ float dropout_mask(int which, int j) {
    u32 dk0, dk1, b1, b2;
    threefry2x32(0u, 42u, 0u, (u32)which, dk0, dk1);
    threefry2x32(dk0, dk1, 0u, (u32)j, b1, b2);
    u32 bits = b1 ^ b2;
    float u = __uint_as_float((bits >> 9) | 0x3f800000u) - 1.0f;
    return (u < 0.5f) ? 2.0f : 0.0f;
}

// ============== L0: prep = btprep (blocks 0..159) + prenet (160..223) ========
template<typename T>
__device__ void prep_impl(const T* wm, const T* wq, u16* BTwm, u16* BTwq,
                          const T* x, const T* w1, const T* pb1, const T* w2, const T* pb2,
                          u16* Ab0, float* shbuf) {
    int bid = blockIdx.x, tid = threadIdx.x;
    if (bid < 160) {
        int gid = bid * 256 + tid;
        const T* src; u16* dst; int L, kc, at;
        if (gid < 8192) { L = gid & 63; kc = (gid >> 6) & 15; at = gid >> 10; src = wm; dst = BTwm + (size_t)gid * 8; }
        else { int g = gid - 8192; L = g & 63; kc = (g >> 6) & 63; at = g >> 12; src = wq; dst = BTwq + (size_t)g * 8; }
        int col = at * 16 + (L & 15);
        int krow = kc * 32 + (L >> 4) * 8;
        u16 v[8];
        #pragma unroll
        for (int j = 0; j < 8; ++j) v[j] = f2bu(ldv(src, (size_t)(krow + j) * DA_ + col));
        uint4 pk;
        pk.x = v[0] | ((u32)v[1] << 16); pk.y = v[2] | ((u32)v[3] << 16);
        pk.z = v[4] | ((u32)v[5] << 16); pk.w = v[6] | ((u32)v[7] << 16);
        *(uint4*)dst = pk;
    } else {
        int b = bid - 160;
        float* xs = shbuf;            // [80]
        float* hs = shbuf + DM_;      // [128]
        if (tid < DM_) xs[tid] = ldv(x, (size_t)b * DM_ + tid);
        __syncthreads();
        if (tid < DH_) {
            float acc = ldv(pb1, tid);
            #pragma unroll 8
            for (int k = 0; k < DM_; ++k) acc = fmaf(xs[k], ldv(w1, (size_t)k * DH_ + tid), acc);
            acc = fmaxf(acc, 0.f) * dropout_mask(0, b * DH_ + tid);
            hs[tid] = acc;
        }
        __syncthreads();
        if (tid < DP_) {
            float acc2 = ldv(pb2, tid);
            #pragma unroll 8
            for (int k = 0; k < DH_; ++k) acc2 = fmaf(hs[k], ldv(w2, (size_t)k * DP_ + tid), acc2);
            acc2 = fmaxf(acc2, 0.f) * dropout_mask(1, b * DP_ + tid);
            Ab0[(size_t)b * 1664 + tid] = f2bu(acc2);
        }
    }
}
__global__ __launch_bounds__(256) void prep_kernel(const u32* h0r,
        const void* wm, const void* wq, u16* BTwm, u16* BTwq,
        const void* x, const void* w1, const void* pb1, const void* w2, const void* pb2,
        u16* Ab0) {
    __shared__ float shbuf[DM_ + DH_];
    if (sniff_is_f32(h0r))
        prep_impl<float>((const float*)wm, (const float*)wq, BTwm, BTwq, (const float*)x,
                         (const float*)w1, (const float*)pb1, (const float*)w2, (const float*)pb2, Ab0, shbuf);
    else
        prep_impl<bf16>((const bf16*)wm, (const bf16*)wq, BTwm, BTwq, (const bf16*)x,
                        (const bf16*)w1, (const bf16*)pb1, (const bf16*)w2, (const bf16*)pb2, Ab0, shbuf);
}

// ============== L1: fused ctx + Mproj, pipelined, reg-persistent wm ==========
// grid (8, 64), 256 thr = 4 waves. Block = 128 t-rows (2 tiles), 4 steps
// (tile x c-phase), FULLY UNROLLED. Per step: write staged regs -> LDS,
// prefetch next step's 32KB (stays in flight across compute), ctx-FMA from
// LDS, MFMA with wave-persistent B-fragments (wave owns 2 at-tiles, loads
// its 32 wm-fragments ONCE). Mproj stored at each tile end.
template<typename T>
__device__ void ctxproj_impl(const T* mem, const T* w, const u16* BTwm,
                             float* CTXP, u16* Mproj, u16* Alds, float* shw) {
    int tid = threadIdx.x;
    int t0 = blockIdx.x * 128, b = blockIdx.y;
    if (tid < 128) shw[tid] = (t0 + tid < T_) ? ldv(w, (size_t)b * T_ + t0 + tid) : 0.f;
    int wv = tid >> 6, L = tid & 63;
    int m = L & 15, q16 = L >> 4;
    int rg = tid >> 5, cg = tid & 31;
    int srow = (tid >> 5), sc16 = tid & 31;     // staging: thread covers rows srow+8*rr? no: i-based below

    // wave-persistent B-fragments: wave wv owns at-tiles {2wv, 2wv+1}
    bf8_t bw[2][16];
    #pragma unroll
    for (int a2 = 0; a2 < 2; ++a2)
        #pragma unroll
        for (int kc = 0; kc < 16; ++kc)
            bw[a2][kc] = *(const bf8_t*)(BTwm + ((size_t)((wv * 2 + a2) * 16 + kc) * 64 + L) * 8);

    f4_t acc[4][2];
    #pragma unroll
    for (int mt = 0; mt < 4; ++mt)
        #pragma unroll
        for (int a2 = 0; a2 < 2; ++a2) acc[mt][a2] = (f4_t){0.f, 0.f, 0.f, 0.f};
    float cacc[16] = {};
    uint4 st[8];

#define LOADSTEP(S) do {                                                        \
        int tt_ = (S) >> 1, ph_ = (S) & 1;                                      \
        _Pragma("unroll")                                                       \
        for (int rr = 0; rr < 8; ++rr) {                                        \
            int i = rr * 256 + tid;                                             \
            int row = i >> 5, c16 = i & 31;                                     \
            int t = t0 + tt_ * 64 + row;                                        \
            st[rr] = (t < T_) ? ld8bf(mem, (size_t)(b * T_ + t) * DC_ + ph_ * 256 + c16 * 8) \
                              : make_uint4(0u, 0u, 0u, 0u);                     \
        }                                                                       \
    } while (0)

    LOADSTEP(0);
    #pragma unroll
    for (int step = 0; step < 4; ++step) {
        const int tt = step >> 1, ph = step & 1;
        __syncthreads();                        // prior compute done with Alds
        #pragma unroll
        for (int rr = 0; rr < 8; ++rr) {
            int i = rr * 256 + tid;
            int row = i >> 5, c16 = i & 31;
            *(uint4*)(Alds + row * 264 + c16 * 8) = st[rr];
        }
        __syncthreads();
        if (step < 3) {                         // prefetch next step NOW
            if (step == 0) LOADSTEP(1);
            else if (step == 1) LOADSTEP(2);
            else LOADSTEP(3);
        }
        // ctx partial accumulation from LDS (8 rows x 8 cols per thread)
        #pragma unroll
        for (int rr = 0; rr < 8; ++rr) {
            int row = rg * 8 + rr;
            float v[8];
            ld8f_bits((const u16*)Alds, (size_t)row * 264 + cg * 8, v);
            float wvv = shw[tt * 64 + row];
            #pragma unroll
            for (int j = 0; j < 8; ++j) cacc[ph * 8 + j] = fmaf(wvv, v[j], cacc[ph * 8 + j]);
        }
        // MFMA: all 4 m-tiles x 2 at-tiles, static kc
        #pragma unroll
        for (int kcl = 0; kcl < 8; ++kcl) {
            const int kc = ph * 8 + kcl;
            #pragma unroll
            for (int mt = 0; mt < 4; ++mt) {
                bf8_t af = *(const bf8_t*)(Alds + (mt * 16 + m) * 264 + kcl * 32 + q16 * 8);
                #pragma unroll
                for (int a2 = 0; a2 < 2; ++a2)
                    acc[mt][a2] = __builtin_amdgcn_mfma_f32_16x16x32_bf16(af, bw[a2][kc], acc[mt][a2], 0, 0, 0);
            }
        }
        // tile complete (after ph==1): store Mproj, reset acc
        if (ph == 1) {
            #pragma unroll
            for (int mt = 0; mt < 4; ++mt)
                #pragma unroll
                for (int a2 = 0; a2 < 2; ++a2) {
                    #pragma unroll
                    for (int r = 0; r < 4; ++r) {
                        int trow = t0 + tt * 64 + mt * 16 + q16 * 4 + r;
                        if (trow < T_)
                            Mproj[(size_t)(b * T_ + trow) * DA_ + (wv * 2 + a2) * 16 + m] = f2bu(acc[mt][a2][r]);
                    }
                    acc[mt][a2] = (f4_t){0.f, 0.f, 0.f, 0.f};
                }
        }
    }
#undef LOADSTEP
    (void)srow; (void)sc16;
    // ctx partial reduce through reused LDS -> CTXP[chunk][b][c]
    __syncthreads();
    float* part = (float*)Alds;   // 8 groups x 512 cols = 16 KB
    #pragma unroll
    for (int ph = 0; ph < 2; ++ph)
        #pragma unroll
        for (int j = 0; j < 8; ++j)
            part[rg * 512 + ph * 256 + cg * 8 + j] = cacc[ph * 8 + j];
    __syncthreads();
    int c = tid * 2;
    float s0 = 0.f, s1 = 0.f;
    #pragma unroll
    for (int gg = 0; gg < 8; ++gg) { s0 += part[gg * 512 + c]; s1 += part[gg * 512 + c + 1]; }
    *(float2*)&CTXP[((size_t)blockIdx.x * 64 + b) * DC_ + c] = make_float2(s0, s1);
}
// separate kernels so f32-path register pressure can't inflate the bf16 path
__global__ __launch_bounds__(256, 2) void ctxproj_bf16_kernel(const u32* h0r,
        const void* mem, const void* w, const u16* BTwm, float* CTXP, u16* Mproj) {
    __shared__ __align__(16) u16 Alds[64 * 264];
    __shared__ float shw[128];
    if (sniff_is_f32(h0r)) return;
    ctxproj_impl<bf16>((const bf16*)mem, (const bf16*)w, BTwm, CTXP, Mproj, Alds, shw);
}
__global__ __launch_bounds__(256, 2) void ctxproj_f32_kernel(const u32* h0r,
        const void* mem, const void* w, const u16* BTwm, float* CTXP, u16* Mproj) {
    __shared__ __align__(16) u16 Alds[64 * 264];
    __shared__ float shw[128];
    if (!sniff_is_f32(h0r)) return;
    ctxproj_impl<float>((const float*)mem, (const float*)w, BTwm, CTXP, Mproj, Alds, shw);
}

// ============== L2: pack0 = ctx reduce + A-buffer packing + xdec tail zeros ==
template<typename T>
__device__ void pack0_impl(const float* CTXP, const T* h0p, const T* h1p,
                           u16* Ab0, u16* Ab1, T* out) {
    int b = blockIdx.x, tid = threadIdx.x;
    T* ctxout = out + O_CTX;
    T* xdec = out + O_XDEC;
    for (int c = tid; c < DC_; c += 256) {
        float s = 0.f;
        #pragma unroll
        for (int t = 0; t < 8; ++t) s += CTXP[((size_t)t * 64 + b) * DC_ + c];
        u16 bv = f2bu(s);
        Ab0[(size_t)b * 1664 + 128 + c] = bv;
        Ab1[(size_t)b * 2560 + 1024 + c] = bv;
        stv(ctxout, (size_t)b * DC_ + c, s);
        stv(xdec, (size_t)b * 2560 + 2048 + c, 0.f);
    }
    for (int u = tid; u < DRN; u += 256) {
        Ab0[(size_t)b * 1664 + 640 + u]  = f2bu(ldv(h0p, (size_t)b * DRN + u));
        Ab1[(size_t)b * 2560 + 1536 + u] = f2bu(ldv(h1p, (size_t)b * DRN + u));
    }
}
__global__ __launch_bounds__(256) void pack0_kernel(const u32* h0r, const float* CTXP,
        const void* h0p, const void* h1p, u16* Ab0, u16* Ab1, void* out) {
    if (sniff_is_f32(h0r))
        pack0_impl<float>(CTXP, (const float*)h0p, (const float*)h1p, Ab0, Ab1, (float*)out);
    else
        pack0_impl<bf16>(CTXP, (const bf16*)h0p, (const bf16*)h1p, Ab0, Ab1, (bf16*)out);
}

// ============== L3/L5: LSTM gate GEMM (T14 prefetch: load ch+1 during compute)
template<typename T>
__device__ void gemm_impl(const u16* Abuf, int K, int L12, const T* Wih, const T* Whh,
                          float* Gs, int nchunks, float (*As)[34], float (*Ws)[64]) {
    int tid = threadIdx.x;
    int n0b = blockIdx.x * 64;
    int kbase = blockIdx.y * (nchunks * 32);
    int cx = tid & 15, ry = tid >> 4;
    int b0 = ry * 4, n0 = cx * 4;
    int a_bb = tid >> 2, a_k8 = (tid & 3) * 8;
    int w_k  = tid >> 3, w_n8 = (tid & 7) * 8;
    float acc[4][4] = {};
    float va[8], vw[8];
    {   // prologue: load chunk 0 into regs
        int k0 = kbase;
        ld8f_bits(Abuf, (size_t)a_bb * K + k0 + a_k8, va);
        int kg = k0 + w_k;
        const T* wr = (kg < L12) ? (Wih + (size_t)kg * G4) : (Whh + (size_t)(kg - L12) * G4);
        ld8f(wr, n0b + w_n8, vw);
    }
    for (int ch = 0; ch < nchunks; ++ch) {
        __syncthreads();                        // prev compute done reading LDS
        #pragma unroll
        for (int j = 0; j < 8; ++j) As[a_bb][a_k8 + j] = va[j];
        #pragma unroll
        for (int j = 0; j < 8; ++j) Ws[w_k][w_n8 + j] = vw[j];
        __syncthreads();
        if (ch + 1 < nchunks) {                 // prefetch next chunk during compute
            int k0 = kbase + (ch + 1) * 32;
            ld8f_bits(Abuf, (size_t)a_bb * K + k0 + a_k8, va);
            int kg = k0 + w_k;
            const T* wr = (kg < L12) ? (Wih + (size_t)kg * G4) : (Whh + (size_t)(kg - L12) * G4);
            ld8f(wr, n0b + w_n8, vw);
        }
        #pragma unroll
        for (int kk = 0; kk < 32; kk += 2) {
            float2 av[4];
            #pragma unroll
            for (int r = 0; r < 4; ++r) av[r] = *(const float2*)&As[b0 + r][kk];
            float4 w0 = *(const float4*)&Ws[kk][n0];
            float4 w1 = *(const float4*)&Ws[kk + 1][n0];
            #pragma unroll
            for (int r = 0; r < 4; ++r) {
                acc[r][0] = fmaf(av[r].x, w0.x, acc[r][0]); acc[r][0] = fmaf(av[r].y, w1.x, acc[r][0]);
                acc[r][1] = fmaf(av[r].x, w0.y, acc[r][1]); acc[r][1] = fmaf(av[r].y, w1.y, acc[r][1]);
                acc[r][2] = fmaf(av[r].x, w0.z, acc[r][2]); acc[r][2] = fmaf(av[r].y, w1.z, acc[r][2]);
                acc[r][3] = fmaf(av[r].x, w0.w, acc[r][3]); acc[r][3] = fmaf(av[r].y, w1.w, acc[r][3]);
            }
        }
    }
    float* outp = Gs + (size_t)blockIdx.y * (64 * G4);
    #pragma unroll
    for (int r = 0; r < 4; ++r)
        *(float4*)&outp[(size_t)(b0 + r) * G4 + n0b + n0] =
            make_float4(acc[r][0], acc[r][1], acc[r][2], acc[r][3]);
}
__global__ __launch_bounds__(256) void gemm_kernel(const u32* h0r, const u16* Abuf,
        int K, int L12, const void* Wih, const void* Whh, float* Gs, int nchunks) {
    __shared__ float As[64][34];
    __shared__ float Ws[32][64];
    if (sniff_is_f32(h0r))
        gemm_impl<float>(Abuf, K, L12, (const float*)Wih, (const float*)Whh, Gs, nchunks, As, Ws);
    else
        gemm_impl<bf16>(Abuf, K, L12, (const bf16*)Wih, (const bf16*)Whh, Gs, nchunks, As, Ws);
}

// ============== L4/L6: split-reduce + gates + zoneout + outputs ==============
template<typename T>
__device__ void gate_impl(const float* Gs, int nsplit, const T* bias, const T* hprev,
                          const T* cprev, T* out, int ho_off, int co_off, int xoff,
                          u16* Hcat, int hoff, u16* Ab1) {
    int idx = blockIdx.x * 256 + threadIdx.x;     // [0, 65536)
    int b = idx >> 10, u = idx & 1023;
    float gi = ldv(bias, u);
    float gf = ldv(bias, 1024 + u);
    float gg = ldv(bias, 2048 + u);
    float go = ldv(bias, 3072 + u);
    for (int s = 0; s < nsplit; ++s) {
        const float* g = Gs + (size_t)s * (64 * G4) + (size_t)b * G4;
        gi += g[u]; gf += g[1024 + u]; gg += g[2048 + u]; go += g[3072 + u];
    }
    float c = ldv(cprev, idx), h = ldv(hprev, idx);
    float si = 1.f / (1.f + expf(-gi));
    float sf = 1.f / (1.f + expf(-gf));
    float so = 1.f / (1.f + expf(-go));
    float cn = sf * c + si * tanhf(gg);
    float hn = so * tanhf(cn);
    float ho = 0.9f * hn + 0.1f * h;
    float co = 0.9f * cn + 0.1f * c;
    stv(out + ho_off, idx, ho);
    stv(out + co_off, idx, co);
    stv(out + O_XDEC, (size_t)b * 2560 + xoff + u, ho);
    u16 hb = f2bu(ho);
    Hcat[(size_t)b * 2048 + hoff + u] = hb;
    if (Ab1 != nullptr) Ab1[(size_t)b * 2560 + u] = hb;
}
__global__ __launch_bounds__(256) void gate_kernel(const u32* h0r, const float* Gs, int nsplit,
        const void* bias, const void* hprev, const void* cprev, void* out,
        int ho_off, int co_off, int xoff, u16* Hcat, int hoff, u16* Ab1) {
    if (sniff_is_f32(h0r))
        gate_impl<float>(Gs, nsplit, (const float*)bias, (const float*)hprev, (const float*)cprev,
                         (float*)out, ho_off, co_off, xoff, Hcat, hoff, Ab1);
    else
        gate_impl<bf16>(Gs, nsplit, (const bf16*)bias, (const bf16*)hprev, (const bf16*)cprev,
                        (bf16*)out, ho_off, co_off, xoff, Hcat, hoff, Ab1);
}

// ============== L7: q GEMM (MFMA, dtype-free): QP[s][64][128] ================
__global__ __launch_bounds__(256) void qgemm_kernel(const u16* Hcat, const u16* BTwq, float* QP) {
    int tid = threadIdx.x;
    int w = tid >> 6, L = tid & 63;
    int m = L & 15, q16 = L >> 4;
    f4_t acc[8];
    #pragma unroll
    for (int at = 0; at < 8; ++at) acc[at] = (f4_t){0.f, 0.f, 0.f, 0.f};
    #pragma unroll
    for (int kcl = 0; kcl < 8; ++kcl) {
        int kc = blockIdx.x * 8 + kcl;
        bf8_t af = *(const bf8_t*)(Hcat + (size_t)(w * 16 + m) * 2048 + kc * 32 + q16 * 8);
        #pragma unroll
        for (int at = 0; at < 8; ++at) {
            bf8_t bfrag = *(const bf8_t*)(BTwq + ((size_t)(at * 64 + kc) * 64 + L) * 8);
            acc[at] = __builtin_amdgcn_mfma_f32_16x16x32_bf16(af, bfrag, acc[at], 0, 0, 0);
        }
    }
    #pragma unroll
    for (int at = 0; at < 8; ++at)
        #pragma unroll
        for (int r = 0; r < 4; ++r)
            QP[((size_t)blockIdx.x * 64 + w * 16 + q16 * 4 + r) * DA_ + at * 16 + m] = acc[at][r];
}

// ============== L8: attention epilogue (tanh-dot-sigmoid) + fused wnew =======
template<typename T>
__device__ void attn_impl(const u16* Mproj, const float* QP, const T* ab, const T* av,
                          const T* w, T* out, float* qa, float* avl, float* psh) {
    int tid = threadIdx.x;
    int t0 = blockIdx.x * 64, b = blockIdx.y;
    T* wout = out + O_WN;
    if (tid < DA_) {
        float s = ldv(ab, tid);
        #pragma unroll
        for (int s8 = 0; s8 < 8; ++s8) s += QP[((size_t)s8 * 64 + b) * DA_ + tid];
        qa[tid] = s;
        avl[tid] = ldv(av, tid);
    }
    __syncthreads();
    int quad = tid & 3, r = tid >> 2;   // 4 threads per row, 32 a each
    #pragma unroll
    for (int rbase = 0; rbase < 2; ++rbase) {
        int rrow = (rbase == 0) ? r : 64;          // row 64 handled by r==0 quads
        bool act = (rbase == 0) || (r == 0);
        int t = t0 - 1 + rrow;
        float e = 0.f;
        if (act && t >= 0 && t < T_) {
            #pragma unroll
            for (int a8 = 0; a8 < 4; ++a8) {
                float v[8];
                ld8f_bits(Mproj, (size_t)(b * T_ + t) * DA_ + quad * 32 + a8 * 8, v);
                #pragma unroll
                for (int j = 0; j < 8; ++j) {
                    int a = quad * 32 + a8 * 8 + j;
                    e = fmaf(avl[a], tanhf(qa[a] + v[j]), e);
                }
            }
        }
        e += __shfl_xor(e, 1);
        e += __shfl_xor(e, 2);
        if (act && quad == 0 && t >= 0 && t < T_) psh[rrow] = 1.f / (1.f + expf(-e));
    }
    __syncthreads();
    if (tid < 64) {
        int t = t0 + tid;
        if (t < T_) {
            float val = ldv(w, (size_t)b * T_ + t) * psh[tid + 1];
            if (t > 0) val = fmaf(ldv(w, (size_t)b * T_ + t - 1), 1.f - psh[tid], val);
            stv(wout, (size_t)b * T_ + t, val);
        }
    }
}
__global__ __launch_bounds__(256) void attn_kernel(const u32* h0r, const u16* Mproj,
        const float* QP, const void* ab, const void* av, const void* w, void* out) {
    __shared__ float qa[DA_];
    __shared__ float avl[DA_];
    __shared__ float psh[66];
    if (sniff_is_f32(h0r))
        attn_impl<float>(Mproj, QP, (const float*)ab, (const float*)av, (const float*)w,
                         (float*)out, qa, avl, psh);
    else
        attn_impl<bf16>(Mproj, QP, (const bf16*)ab, (const bf16*)av, (const bf16*)w,
                        (bf16*)out, qa, avl, psh);
}

// ---------------- launch -----------------------------------------------------
extern "C" void kernel_launch(void* const* d_in, const int* in_sizes, int n_in,
                              void* d_out, int out_size, void* d_ws, size_t ws_size,
                              hipStream_t stream) {
    (void)in_sizes; (void)n_in; (void)out_size; (void)ws_size;

    // workspace layout (f32 units). Total 9,244,672 f32 = 37.0 MiB.
    float* wsf   = (float*)d_ws;
    float* GS    = wsf;                        // 16 x 262144 (per-split gate buffers)
    float* CTXP  = wsf + 4194304;              // 8 x 64 x 512 ctx partials (region holds 16)
    float* QP    = wsf + 4718592;              // 8 x 64 x 128 q partials
    u16*   MPROJ = (u16*)(wsf + 4784128);      // 64 x 1000 x 128 bf16
    u16*   AB0   = (u16*)(wsf + 8880128);      // 64 x 1664 bf16
    u16*   AB1   = (u16*)(wsf + 8933376);      // 64 x 2560 bf16
    u16*   HCAT  = (u16*)(wsf + 9015296);      // 64 x 2048 bf16
    u16*   BTWM  = (u16*)(wsf + 9080832);      // 65536 bf16
    u16*   BTWQ  = (u16*)(wsf + 9113600);      // 262144 bf16

    const u32* H0R = (const u32*)d_in[2];

    // L0: B-fragment prep (wm,wq) + prenet -> AB0[:,0:128]
    prep_kernel<<<224, 256, 0, stream>>>(H0R, d_in[19], d_in[18], BTWM, BTWQ,
                                         d_in[0], d_in[8], d_in[9], d_in[10], d_in[11], AB0);
    // L1: fused ctx + Mproj, single pass over memory (dtype-split kernels)
    ctxproj_bf16_kernel<<<dim3(8, 64), 256, 0, stream>>>(H0R, d_in[6], d_in[1], BTWM, CTXP, MPROJ);
    ctxproj_f32_kernel <<<dim3(8, 64), 256, 0, stream>>>(H0R, d_in[6], d_in[1], BTWM, CTXP, MPROJ);
    // L2: ctx reduce + A-buffer packing + ctx out + xdec tail zeros
    pack0_kernel<<<64, 256, 0, stream>>>(H0R, CTXP, d_in[2], d_in[4], AB0, AB1, d_out);
    // L3/L4: LSTM layer 0 (K=1664, 13 splits x 4 chunks)
    gemm_kernel<<<dim3(64, 13), 256, 0, stream>>>(H0R, AB0, 1664, 640, d_in[12], d_in[13], GS, 4);
    gate_kernel<<<256, 256, 0, stream>>>(H0R, GS, 13, d_in[14], d_in[2], d_in[3], d_out,
                                         O_H0, O_C0, 0, HCAT, 0, AB1);
    // L5/L6: LSTM layer 1 (K=2560, 16 splits x 5 chunks)
    gemm_kernel<<<dim3(64, 16), 256, 0, stream>>>(H0R, AB1, 2560, 1536, d_in[15], d_in[16], GS, 5);
    gate_kernel<<<256, 256, 0, stream>>>(H0R, GS, 16, d_in[17], d_in[4], d_in[5], d_out,
                                         O_H1, O_C1, 1024, HCAT, 1024, (u16*)nullptr);
    // L7: q = Hcat @ wq (8 k-splits, no atomics)
    qgemm_kernel<<<8, 256, 0, stream>>>(HCAT, BTWQ, QP);
    // L8: p = sigmoid(v . tanh(q + Mproj)) fused with w_new
    attn_kernel<<<dim3(16, 64), 256, 0, stream>>>(H0R, MPROJ, QP, d_in[20], d_in[21], d_in[1], d_out);
}

// Round 7
// 389.489 us; speedup vs baseline: 1.0611x; 1.0586x over previous
//
#include <hip/hip_runtime.h>
#include <hip/hip_bf16.h>
#include <stdint.h>

// Problem constants
#define B_  64
#define T_  1000
#define DC_ 512
#define DM_ 80
#define DP_ 128
#define DH_ 128
#define DA_ 128
#define DRN 1024
#define G4  4096

typedef __hip_bfloat16 bf16;
typedef unsigned short u16;
typedef unsigned int   u32;

// MFMA fragment types
typedef short bf8_t __attribute__((ext_vector_type(8)));
typedef float f4_t  __attribute__((ext_vector_type(4)));

// out element offsets: x_dec, ctx, w_new, h0n, c0n, h1n, c1n
#define O_XDEC 0
#define O_CTX  163840
#define O_WN   196608
#define O_H0   260608
#define O_C0   326144
#define O_H1   391680
#define O_C1   457216

__device__ __forceinline__ float b2f(bf16 v) { return __bfloat162float(v); }
__device__ __forceinline__ bf16  f2b(float v) { return __float2bfloat16(v); }
__device__ __forceinline__ u16   f2bu(float v) { return __builtin_bit_cast(u16, __float2bfloat16(v)); }

__device__ __forceinline__ float ldv(const float* p, size_t i) { return p[i]; }
__device__ __forceinline__ float ldv(const bf16*  p, size_t i) { return b2f(p[i]); }
__device__ __forceinline__ void  stv(float* p, size_t i, float v) { p[i] = v; }
__device__ __forceinline__ void  stv(bf16*  p, size_t i, float v) { p[i] = f2b(v); }

// load 8 consecutive elems (i must be 8-aligned) as packed bf16 bits
template<typename T>
__device__ __forceinline__ uint4 ld8bf(const T* p, size_t i) {
    if constexpr (sizeof(T) == 2) {
        return *(const uint4*)((const u16*)p + i);
    } else {
        float4 a = *(const float4*)(p + i);
        float4 b = *(const float4*)(p + i + 4);
        uint4 r;
        r.x = (u32)f2bu(a.x) | ((u32)f2bu(a.y) << 16);
        r.y = (u32)f2bu(a.z) | ((u32)f2bu(a.w) << 16);
        r.z = (u32)f2bu(b.x) | ((u32)f2bu(b.y) << 16);
        r.w = (u32)f2bu(b.z) | ((u32)f2bu(b.w) << 16);
        return r;
    }
}
// load 8 consecutive elems as f32
template<typename T>
__device__ __forceinline__ void ld8f(const T* p, size_t i, float* o) {
    if constexpr (sizeof(T) == 2) {
        uint4 u = *(const uint4*)((const u16*)p + i);
        o[0] = __uint_as_float(u.x << 16); o[1] = __uint_as_float(u.x & 0xffff0000u);
        o[2] = __uint_as_float(u.y << 16); o[3] = __uint_as_float(u.y & 0xffff0000u);
        o[4] = __uint_as_float(u.z << 16); o[5] = __uint_as_float(u.z & 0xffff0000u);
        o[6] = __uint_as_float(u.w << 16); o[7] = __uint_as_float(u.w & 0xffff0000u);
    } else {
        float4 a = *(const float4*)(p + i);
        float4 b = *(const float4*)(p + i + 4);
        o[0]=a.x; o[1]=a.y; o[2]=a.z; o[3]=a.w; o[4]=b.x; o[5]=b.y; o[6]=b.z; o[7]=b.w;
    }
}
__device__ __forceinline__ void ld8f_bits(const u16* p, size_t i, float* o) {
    uint4 u = *(const uint4*)(p + i);
    o[0] = __uint_as_float(u.x << 16); o[1] = __uint_as_float(u.x & 0xffff0000u);
    o[2] = __uint_as_float(u.y << 16); o[3] = __uint_as_float(u.y & 0xffff0000u);
    o[4] = __uint_as_float(u.z << 16); o[5] = __uint_as_float(u.z & 0xffff0000u);
    o[6] = __uint_as_float(u.w << 16); o[7] = __uint_as_float(u.w & 0xffff0000u);
}

// ---------------- per-block dtype sniff (proven heuristic; wave-uniform) -----
__device__ __forceinline__ bool sniff_is_f32(const u32* h0raw) {
    int lane = threadIdx.x & 63;
    int c = 0;
    #pragma unroll
    for (int i = 0; i < 4; ++i) {
        u32 e = (h0raw[lane * 4 + i] >> 7) & 0xFF;
        c += (e >= 100 && e <= 126) ? 1 : 0;
    }
    #pragma unroll
    for (int s = 1; s < 64; s <<= 1) c += __shfl_xor(c, s);
    return c < 128;
}

// ---------------- Threefry-2x32 (bit-exact vs JAX — do not touch) ------------
__device__ __forceinline__ u32 rotl32(u32 v, int r) { return (v << r) | (v >> (32 - r)); }
__device__ __forceinline__ void threefry2x32(u32 k0, u32 k1, u32 x0, u32 x1, u32& y0, u32& y1) {
    u32 ks2 = k0 ^ k1 ^ 0x1BD11BDAu;
    x0 += k0; x1 += k1;
#define TF_R(r) { x0 += x1; x1 = rotl32(x1, r); x1 ^= x0; }
    TF_R(13) TF_R(15) TF_R(26) TF_R(6)
    x0 += k1; x1 += ks2 + 1u;
    TF_R(17) TF_R(29) TF_R(16) TF_R(24)
    x0 += ks2; x1 += k0 + 2u;
    TF_R(13) TF_R(15) TF_R(26) TF_R(6)
    x0 += k0; x1 += k1 + 3u;
    TF_R(17) TF_R(29) TF_R(16) TF_R(24)
    x0 += k1; x1 += ks2 + 4u;
    TF_R(13) TF_R(15) TF_R(26) TF_R(6)
    x0 += ks2; x1 += k0 + 5u;
#undef TF_R
    y0 = x0; y1 = x1;
}
__device__ __forceinline__ float dropout_mask(int which, int j) {
    u32 dk0, dk1, b1, b2;
    threefry2x32(0u, 42u, 0u, (u32)which, dk0, dk1);
    threefry2x32(dk0, dk1, 0u, (u32)j, b1, b2);
    u32 bits = b1 ^ b2;
    float u = __uint_as_float((bits >> 9) | 0x3f800000u) - 1.0f;
    return (u < 0.5f) ? 2.0f : 0.0f;
}

// ============== L0: prep = btprep (blocks 0..159) + prenet (160..223) ========
template<typename T>
__device__ void prep_impl(const T* wm, const T* wq, u16* BTwm, u16* BTwq,
                          const T* x, const T* w1, const T* pb1, const T* w2, const T* pb2,
                          u16* Ab0, float* shbuf) {
    int bid = blockIdx.x, tid = threadIdx.x;
    if (bid < 160) {
        int gid = bid * 256 + tid;
        const T* src; u16* dst; int L, kc, at;
        if (gid < 8192) { L = gid & 63; kc = (gid >> 6) & 15; at = gid >> 10; src = wm; dst = BTwm + (size_t)gid * 8; }
        else { int g = gid - 8192; L = g & 63; kc = (g >> 6) & 63; at = g >> 12; src = wq; dst = BTwq + (size_t)g * 8; }
        int col = at * 16 + (L & 15);
        int krow = kc * 32 + (L >> 4) * 8;
        u16 v[8];
        #pragma unroll
        for (int j = 0; j < 8; ++j) v[j] = f2bu(ldv(src, (size_t)(krow + j) * DA_ + col));
        uint4 pk;
        pk.x = v[0] | ((u32)v[1] << 16); pk.y = v[2] | ((u32)v[3] << 16);
        pk.z = v[4] | ((u32)v[5] << 16); pk.w = v[6] | ((u32)v[7] << 16);
        *(uint4*)dst = pk;
    } else {
        int b = bid - 160;
        float* xs = shbuf;            // [80]
        float* hs = shbuf + DM_;      // [128]
        if (tid < DM_) xs[tid] = ldv(x, (size_t)b * DM_ + tid);
        __syncthreads();
        if (tid < DH_) {
            float acc = ldv(pb1, tid);
            #pragma unroll 8
            for (int k = 0; k < DM_; ++k) acc = fmaf(xs[k], ldv(w1, (size_t)k * DH_ + tid), acc);
            acc = fmaxf(acc, 0.f) * dropout_mask(0, b * DH_ + tid);
            hs[tid] = acc;
        }
        __syncthreads();
        if (tid < DP_) {
            float acc2 = ldv(pb2, tid);
            #pragma unroll 8
            for (int k = 0; k < DH_; ++k) acc2 = fmaf(hs[k], ldv(w2, (size_t)k * DP_ + tid), acc2);
            acc2 = fmaxf(acc2, 0.f) * dropout_mask(1, b * DP_ + tid);
            Ab0[(size_t)b * 1664 + tid] = f2bu(acc2);
        }
    }
}
__global__ __launch_bounds__(256) void prep_kernel(const u32* h0r,
        const void* wm, const void* wq, u16* BTwm, u16* BTwq,
        const void* x, const void* w1, const void* pb1, const void* w2, const void* pb2,
        u16* Ab0) {
    __shared__ float shbuf[DM_ + DH_];
    if (sniff_is_f32(h0r))
        prep_impl<float>((const float*)wm, (const float*)wq, BTwm, BTwq, (const float*)x,
                         (const float*)w1, (const float*)pb1, (const float*)w2, (const float*)pb2, Ab0, shbuf);
    else
        prep_impl<bf16>((const bf16*)wm, (const bf16*)wq, BTwm, BTwq, (const bf16*)x,
                        (const bf16*)w1, (const bf16*)pb1, (const bf16*)w2, (const bf16*)pb2, Ab0, shbuf);
}

// ============== L1: fused ctx + Mproj, pipelined, per-wave reg B-frags =======
// grid (8, 64), 512 thr = 8 waves. Block = 128 t-rows (2 tiles x 2 c-phases =
// 4 steps, fully unrolled). Wave w owns at-tile w: its 16 B-fragments (64
// VGPR) load from global ONCE at block start -> steady-state vmcnt queue
// holds ONLY staging loads; bfrag from regs, af from LDS (lgkmcnt).
// Staging keeps RAW data in regs (f32 converts at write) and prefetches step
// s+1 right after the write barrier so loads span the whole compute phase.
template<typename T>
__device__ void ctxproj_impl(const T* mem, const T* w, const u16* BTwm,
                             float* CTXP, u16* Mproj, u16* Alds, float* shw) {
    int tid = threadIdx.x;
    int t0 = blockIdx.x * 128, b = blockIdx.y;
    if (tid < 128) shw[tid] = (t0 + tid < T_) ? ldv(w, (size_t)b * T_ + t0 + tid) : 0.f;
    int L = tid & 63;
    int m = L & 15, q16 = L >> 4;
    int wat = tid >> 6;                 // wave's at-tile (0..7)
    int rg = tid >> 5, cg = tid & 31;   // ctx ownership: 16 row-groups x 32 col-groups

    // wave-persistent B-fragments for at-tile `wat` (16 frags = 64 VGPR, static idx)
    bf8_t bw[16];
    #pragma unroll
    for (int kc = 0; kc < 16; ++kc)
        bw[kc] = *(const bf8_t*)(BTwm + ((size_t)(wat * 16 + kc) * 64 + L) * 8);

    f4_t acc[4];
    #pragma unroll
    for (int mt = 0; mt < 4; ++mt) acc[mt] = (f4_t){0.f, 0.f, 0.f, 0.f};
    float cacc[16] = {};
    uint4  stb[4];       // bf16 raw staging
    float4 stf[8];       // f32 raw staging (pairs)

#define LOADSTEP(S) do {                                                         \
        const int tt_ = (S) >> 1, ph_ = (S) & 1;                                 \
        _Pragma("unroll")                                                        \
        for (int rr = 0; rr < 4; ++rr) {                                         \
            int i = rr * 512 + tid;                                              \
            int row = i >> 5, c16 = i & 31;                                      \
            int t = t0 + tt_ * 64 + row;                                         \
            size_t base = (size_t)(b * T_ + ((t < T_) ? t : 0)) * DC_ + ph_ * 256 + c16 * 8; \
            if constexpr (sizeof(T) == 2) {                                      \
                stb[rr] = (t < T_) ? *(const uint4*)((const u16*)mem + base)     \
                                   : make_uint4(0u, 0u, 0u, 0u);                 \
            } else {                                                             \
                if (t < T_) { stf[2*rr]   = *(const float4*)(mem + base);        \
                              stf[2*rr+1] = *(const float4*)(mem + base + 4); }  \
                else { stf[2*rr] = make_float4(0.f,0.f,0.f,0.f);                 \
                       stf[2*rr+1] = make_float4(0.f,0.f,0.f,0.f); }             \
            }                                                                    \
        }                                                                        \
    } while (0)

    LOADSTEP(0);
    #pragma unroll
    for (int step = 0; step < 4; ++step) {
        const int tt = step >> 1, ph = step & 1;
        __syncthreads();                  // prior compute done reading Alds; (step0: shw ready)
        #pragma unroll
        for (int rr = 0; rr < 4; ++rr) {
            int i = rr * 512 + tid;
            int row = i >> 5, c16 = i & 31;
            uint4 v;
            if constexpr (sizeof(T) == 2) {
                v = stb[rr];
            } else {
                float4 a = stf[2*rr], bb = stf[2*rr+1];
                v.x = (u32)f2bu(a.x)  | ((u32)f2bu(a.y)  << 16);
                v.y = (u32)f2bu(a.z)  | ((u32)f2bu(a.w)  << 16);
                v.z = (u32)f2bu(bb.x) | ((u32)f2bu(bb.y) << 16);
                v.w = (u32)f2bu(bb.z) | ((u32)f2bu(bb.w) << 16);
            }
            *(uint4*)(Alds + row * 264 + c16 * 8) = v;
        }
        __syncthreads();
        if (step == 0) LOADSTEP(1);       // prefetch: loads span the compute below
        else if (step == 1) LOADSTEP(2);
        else if (step == 2) LOADSTEP(3);
        // ctx partial accumulation from LDS (4 rows x 8 cols per thread)
        #pragma unroll
        for (int rr = 0; rr < 4; ++rr) {
            int row = rg * 4 + rr;
            float v[8];
            ld8f_bits((const u16*)Alds, (size_t)row * 264 + cg * 8, v);
            float wvv = shw[tt * 64 + row];
            #pragma unroll
            for (int j = 0; j < 8; ++j) cacc[ph * 8 + j] = fmaf(wvv, v[j], cacc[ph * 8 + j]);
        }
        // MFMA: wave's at-tile x all 4 m-tiles; af from LDS, bfrag from regs
        #pragma unroll
        for (int kcl = 0; kcl < 8; ++kcl) {
            const int kc = ph * 8 + kcl;
            #pragma unroll
            for (int mt = 0; mt < 4; ++mt) {
                bf8_t af = *(const bf8_t*)(Alds + (mt * 16 + m) * 264 + kcl * 32 + q16 * 8);
                acc[mt] = __builtin_amdgcn_mfma_f32_16x16x32_bf16(af, bw[kc], acc[mt], 0, 0, 0);
            }
        }
        // tile complete (ph==1): store Mproj (proven C/D layout), reset acc
        if (ph == 1) {
            #pragma unroll
            for (int mt = 0; mt < 4; ++mt) {
                #pragma unroll
                for (int r = 0; r < 4; ++r) {
                    int trow = t0 + tt * 64 + mt * 16 + q16 * 4 + r;
                    if (trow < T_)
                        Mproj[(size_t)(b * T_ + trow) * DA_ + wat * 16 + m] = f2bu(acc[mt][r]);
                }
                acc[mt] = (f4_t){0.f, 0.f, 0.f, 0.f};
            }
        }
    }
#undef LOADSTEP
    // ctx partial reduce through reused Alds -> CTXP[chunk][b][c]
    __syncthreads();
    float* part = (float*)Alds;   // 16 groups x 512 cols = 32 KB (fits 33 KB)
    #pragma unroll
    for (int ph = 0; ph < 2; ++ph)
        #pragma unroll
        for (int j = 0; j < 8; ++j)
            part[rg * 512 + ph * 256 + cg * 8 + j] = cacc[ph * 8 + j];
    __syncthreads();
    int c = tid;                  // 0..511
    float s = 0.f;
    #pragma unroll
    for (int gg = 0; gg < 16; ++gg) s += part[gg * 512 + c];
    CTXP[((size_t)blockIdx.x * 64 + b) * DC_ + c] = s;
}
// separate kernels so f32-path register pressure can't inflate the bf16 path
__global__ __launch_bounds__(512, 1) void ctxproj_bf16_kernel(const u32* h0r,
        const void* mem, const void* w, const u16* BTwm, float* CTXP, u16* Mproj) {
    __shared__ __align__(16) u16 Alds[64 * 264];
    __shared__ float shw[128];
    if (sniff_is_f32(h0r)) return;
    ctxproj_impl<bf16>((const bf16*)mem, (const bf16*)w, BTwm, CTXP, Mproj, Alds, shw);
}
__global__ __launch_bounds__(512, 1) void ctxproj_f32_kernel(const u32* h0r,
        const void* mem, const void* w, const u16* BTwm, float* CTXP, u16* Mproj) {
    __shared__ __align__(16) u16 Alds[64 * 264];
    __shared__ float shw[128];
    if (!sniff_is_f32(h0r)) return;
    ctxproj_impl<float>((const float*)mem, (const float*)w, BTwm, CTXP, Mproj, Alds, shw);
}

// ============== L2: pack0 = ctx reduce + A-buffer packing + xdec tail zeros ==
template<typename T>
__device__ void pack0_impl(const float* CTXP, const T* h0p, const T* h1p,
                           u16* Ab0, u16* Ab1, T* out) {
    int b = blockIdx.x, tid = threadIdx.x;
    T* ctxout = out + O_CTX;
    T* xdec = out + O_XDEC;
    for (int c = tid; c < DC_; c += 256) {
        float s = 0.f;
        #pragma unroll
        for (int t = 0; t < 8; ++t) s += CTXP[((size_t)t * 64 + b) * DC_ + c];
        u16 bv = f2bu(s);
        Ab0[(size_t)b * 1664 + 128 + c] = bv;
        Ab1[(size_t)b * 2560 + 1024 + c] = bv;
        stv(ctxout, (size_t)b * DC_ + c, s);
        stv(xdec, (size_t)b * 2560 + 2048 + c, 0.f);
    }
    for (int u = tid; u < DRN; u += 256) {
        Ab0[(size_t)b * 1664 + 640 + u]  = f2bu(ldv(h0p, (size_t)b * DRN + u));
        Ab1[(size_t)b * 2560 + 1536 + u] = f2bu(ldv(h1p, (size_t)b * DRN + u));
    }
}
__global__ __launch_bounds__(256) void pack0_kernel(const u32* h0r, const float* CTXP,
        const void* h0p, const void* h1p, u16* Ab0, u16* Ab1, void* out) {
    if (sniff_is_f32(h0r))
        pack0_impl<float>(CTXP, (const float*)h0p, (const float*)h1p, Ab0, Ab1, (float*)out);
    else
        pack0_impl<bf16>(CTXP, (const bf16*)h0p, (const bf16*)h1p, Ab0, Ab1, (bf16*)out);
}

// ============== L3/L5: LSTM gate GEMM (T14 prefetch: load ch+1 during compute)
template<typename T>
__device__ void gemm_impl(const u16* Abuf, int K, int L12, const T* Wih, const T* Whh,
                          float* Gs, int nchunks, float (*As)[34], float (*Ws)[64]) {
    int tid = threadIdx.x;
    int n0b = blockIdx.x * 64;
    int kbase = blockIdx.y * (nchunks * 32);
    int cx = tid & 15, ry = tid >> 4;
    int b0 = ry * 4, n0 = cx * 4;
    int a_bb = tid >> 2, a_k8 = (tid & 3) * 8;
    int w_k  = tid >> 3, w_n8 = (tid & 7) * 8;
    float acc[4][4] = {};
    float va[8], vw[8];
    {   // prologue: load chunk 0 into regs
        int k0 = kbase;
        ld8f_bits(Abuf, (size_t)a_bb * K + k0 + a_k8, va);
        int kg = k0 + w_k;
        const T* wr = (kg < L12) ? (Wih + (size_t)kg * G4) : (Whh + (size_t)(kg - L12) * G4);
        ld8f(wr, n0b + w_n8, vw);
    }
    for (int ch = 0; ch < nchunks; ++ch) {
        __syncthreads();                        // prev compute done reading LDS
        #pragma unroll
        for (int j = 0; j < 8; ++j) As[a_bb][a_k8 + j] = va[j];
        #pragma unroll
        for (int j = 0; j < 8; ++j) Ws[w_k][w_n8 + j] = vw[j];
        __syncthreads();
        if (ch + 1 < nchunks) {                 // prefetch next chunk during compute
            int k0 = kbase + (ch + 1) * 32;
            ld8f_bits(Abuf, (size_t)a_bb * K + k0 + a_k8, va);
            int kg = k0 + w_k;
            const T* wr = (kg < L12) ? (Wih + (size_t)kg * G4) : (Whh + (size_t)(kg - L12) * G4);
            ld8f(wr, n0b + w_n8, vw);
        }
        #pragma unroll
        for (int kk = 0; kk < 32; kk += 2) {
            float2 av[4];
            #pragma unroll
            for (int r = 0; r < 4; ++r) av[r] = *(const float2*)&As[b0 + r][kk];
            float4 w0 = *(const float4*)&Ws[kk][n0];
            float4 w1 = *(const float4*)&Ws[kk + 1][n0];
            #pragma unroll
            for (int r = 0; r < 4; ++r) {
                acc[r][0] = fmaf(av[r].x, w0.x, acc[r][0]); acc[r][0] = fmaf(av[r].y, w1.x, acc[r][0]);
                acc[r][1] = fmaf(av[r].x, w0.y, acc[r][1]); acc[r][1] = fmaf(av[r].y, w1.y, acc[r][1]);
                acc[r][2] = fmaf(av[r].x, w0.z, acc[r][2]); acc[r][2] = fmaf(av[r].y, w1.z, acc[r][2]);
                acc[r][3] = fmaf(av[r].x, w0.w, acc[r][3]); acc[r][3] = fmaf(av[r].y, w1.w, acc[r][3]);
            }
        }
    }
    float* outp = Gs + (size_t)blockIdx.y * (64 * G4);
    #pragma unroll
    for (int r = 0; r < 4; ++r)
        *(float4*)&outp[(size_t)(b0 + r) * G4 + n0b + n0] =
            make_float4(acc[r][0], acc[r][1], acc[r][2], acc[r][3]);
}
__global__ __launch_bounds__(256) void gemm_kernel(const u32* h0r, const u16* Abuf,
        int K, int L12, const void* Wih, const void* Whh, float* Gs, int nchunks) {
    __shared__ float As[64][34];
    __shared__ float Ws[32][64];
    if (sniff_is_f32(h0r))
        gemm_impl<float>(Abuf, K, L12, (const float*)Wih, (const float*)Whh, Gs, nchunks, As, Ws);
    else
        gemm_impl<bf16>(Abuf, K, L12, (const bf16*)Wih, (const bf16*)Whh, Gs, nchunks, As, Ws);
}

// ============== L4/L6: split-reduce + gates + zoneout + outputs ==============
template<typename T>
__device__ void gate_impl(const float* Gs, int nsplit, const T* bias, const T* hprev,
                          const T* cprev, T* out, int ho_off, int co_off, int xoff,
                          u16* Hcat, int hoff, u16* Ab1) {
    int idx = blockIdx.x * 256 + threadIdx.x;     // [0, 65536)
    int b = idx >> 10, u = idx & 1023;
    float gi = ldv(bias, u);
    float gf = ldv(bias, 1024 + u);
    float gg = ldv(bias, 2048 + u);
    float go = ldv(bias, 3072 + u);
    for (int s = 0; s < nsplit; ++s) {
        const float* g = Gs + (size_t)s * (64 * G4) + (size_t)b * G4;
        gi += g[u]; gf += g[1024 + u]; gg += g[2048 + u]; go += g[3072 + u];
    }
    float c = ldv(cprev, idx), h = ldv(hprev, idx);
    float si = 1.f / (1.f + expf(-gi));
    float sf = 1.f / (1.f + expf(-gf));
    float so = 1.f / (1.f + expf(-go));
    float cn = sf * c + si * tanhf(gg);
    float hn = so * tanhf(cn);
    float ho = 0.9f * hn + 0.1f * h;
    float co = 0.9f * cn + 0.1f * c;
    stv(out + ho_off, idx, ho);
    stv(out + co_off, idx, co);
    stv(out + O_XDEC, (size_t)b * 2560 + xoff + u, ho);
    u16 hb = f2bu(ho);
    Hcat[(size_t)b * 2048 + hoff + u] = hb;
    if (Ab1 != nullptr) Ab1[(size_t)b * 2560 + u] = hb;
}
__global__ __launch_bounds__(256) void gate_kernel(const u32* h0r, const float* Gs, int nsplit,
        const void* bias, const void* hprev, const void* cprev, void* out,
        int ho_off, int co_off, int xoff, u16* Hcat, int hoff, u16* Ab1) {
    if (sniff_is_f32(h0r))
        gate_impl<float>(Gs, nsplit, (const float*)bias, (const float*)hprev, (const float*)cprev,
                         (float*)out, ho_off, co_off, xoff, Hcat, hoff, Ab1);
    else
        gate_impl<bf16>(Gs, nsplit, (const bf16*)bias, (const bf16*)hprev, (const bf16*)cprev,
                        (bf16*)out, ho_off, co_off, xoff, Hcat, hoff, Ab1);
}

// ============== L7: q GEMM (MFMA, dtype-free): QP[s][64][128] ================
__global__ __launch_bounds__(256) void qgemm_kernel(const u16* Hcat, const u16* BTwq, float* QP) {
    int tid = threadIdx.x;
    int w = tid >> 6, L = tid & 63;
    int m = L & 15, q16 = L >> 4;
    f4_t acc[8];
    #pragma unroll
    for (int at = 0; at < 8; ++at) acc[at] = (f4_t){0.f, 0.f, 0.f, 0.f};
    #pragma unroll
    for (int kcl = 0; kcl < 8; ++kcl) {
        int kc = blockIdx.x * 8 + kcl;
        bf8_t af = *(const bf8_t*)(Hcat + (size_t)(w * 16 + m) * 2048 + kc * 32 + q16 * 8);
        #pragma unroll
        for (int at = 0; at < 8; ++at) {
            bf8_t bfrag = *(const bf8_t*)(BTwq + ((size_t)(at * 64 + kc) * 64 + L) * 8);
            acc[at] = __builtin_amdgcn_mfma_f32_16x16x32_bf16(af, bfrag, acc[at], 0, 0, 0);
        }
    }
    #pragma unroll
    for (int at = 0; at < 8; ++at)
        #pragma unroll
        for (int r = 0; r < 4; ++r)
            QP[((size_t)blockIdx.x * 64 + w * 16 + q16 * 4 + r) * DA_ + at * 16 + m] = acc[at][r];
}

// ============== L8: attention epilogue (tanh-dot-sigmoid) + fused wnew =======
template<typename T>
__device__ void attn_impl(const u16* Mproj, const float* QP, const T* ab, const T* av,
                          const T* w, T* out, float* qa, float* avl, float* psh) {
    int tid = threadIdx.x;
    int t0 = blockIdx.x * 64, b = blockIdx.y;
    T* wout = out + O_WN;
    if (tid < DA_) {
        float s = ldv(ab, tid);
        #pragma unroll
        for (int s8 = 0; s8 < 8; ++s8) s += QP[((size_t)s8 * 64 + b) * DA_ + tid];
        qa[tid] = s;
        avl[tid] = ldv(av, tid);
    }
    __syncthreads();
    int quad = tid & 3, r = tid >> 2;   // 4 threads per row, 32 a each
    #pragma unroll
    for (int rbase = 0; rbase < 2; ++rbase) {
        int rrow = (rbase == 0) ? r : 64;          // row 64 handled by r==0 quads
        bool act = (rbase == 0) || (r == 0);
        int t = t0 - 1 + rrow;
        float e = 0.f;
        if (act && t >= 0 && t < T_) {
            #pragma unroll
            for (int a8 = 0; a8 < 4; ++a8) {
                float v[8];
                ld8f_bits(Mproj, (size_t)(b * T_ + t) * DA_ + quad * 32 + a8 * 8, v);
                #pragma unroll
                for (int j = 0; j < 8; ++j) {
                    int a = quad * 32 + a8 * 8 + j;
                    e = fmaf(avl[a], tanhf(qa[a] + v[j]), e);
                }
            }
        }
        e += __shfl_xor(e, 1);
        e += __shfl_xor(e, 2);
        if (act && quad == 0 && t >= 0 && t < T_) psh[rrow] = 1.f / (1.f + expf(-e));
    }
    __syncthreads();
    if (tid < 64) {
        int t = t0 + tid;
        if (t < T_) {
            float val = ldv(w, (size_t)b * T_ + t) * psh[tid + 1];
            if (t > 0) val = fmaf(ldv(w, (size_t)b * T_ + t - 1), 1.f - psh[tid], val);
            stv(wout, (size_t)b * T_ + t, val);
        }
    }
}
__global__ __launch_bounds__(256) void attn_kernel(const u32* h0r, const u16* Mproj,
        const float* QP, const void* ab, const void* av, const void* w, void* out) {
    __shared__ float qa[DA_];
    __shared__ float avl[DA_];
    __shared__ float psh[66];
    if (sniff_is_f32(h0r))
        attn_impl<float>(Mproj, QP, (const float*)ab, (const float*)av, (const float*)w,
                         (float*)out, qa, avl, psh);
    else
        attn_impl<bf16>(Mproj, QP, (const bf16*)ab, (const bf16*)av, (const bf16*)w,
                        (bf16*)out, qa, avl, psh);
}

// ---------------- launch -----------------------------------------------------
extern "C" void kernel_launch(void* const* d_in, const int* in_sizes, int n_in,
                              void* d_out, int out_size, void* d_ws, size_t ws_size,
                              hipStream_t stream) {
    (void)in_sizes; (void)n_in; (void)out_size; (void)ws_size;

    // workspace layout (f32 units). Total 9,244,672 f32 = 37.0 MiB.
    float* wsf   = (float*)d_ws;
    float* GS    = wsf;                        // 16 x 262144 (per-split gate buffers)
    float* CTXP  = wsf + 4194304;              // 8 x 64 x 512 ctx partials (region holds 16)
    float* QP    = wsf + 4718592;              // 8 x 64 x 128 q partials
    u16*   MPROJ = (u16*)(wsf + 4784128);      // 64 x 1000 x 128 bf16
    u16*   AB0   = (u16*)(wsf + 8880128);      // 64 x 1664 bf16
    u16*   AB1   = (u16*)(wsf + 8933376);      // 64 x 2560 bf16
    u16*   HCAT  = (u16*)(wsf + 9015296);      // 64 x 2048 bf16
    u16*   BTWM  = (u16*)(wsf + 9080832);      // 65536 bf16
    u16*   BTWQ  = (u16*)(wsf + 9113600);      // 262144 bf16

    const u32* H0R = (const u32*)d_in[2];

    // L0: B-fragment prep (wm,wq) + prenet -> AB0[:,0:128]
    prep_kernel<<<224, 256, 0, stream>>>(H0R, d_in[19], d_in[18], BTWM, BTWQ,
                                         d_in[0], d_in[8], d_in[9], d_in[10], d_in[11], AB0);
    // L1: fused ctx + Mproj, single pass over memory (dtype-split kernels)
    ctxproj_bf16_kernel<<<dim3(8, 64), 512, 0, stream>>>(H0R, d_in[6], d_in[1], BTWM, CTXP, MPROJ);
    ctxproj_f32_kernel <<<dim3(8, 64), 512, 0, stream>>>(H0R, d_in[6], d_in[1], BTWM, CTXP, MPROJ);
    // L2: ctx reduce + A-buffer packing + ctx out + xdec tail zeros
    pack0_kernel<<<64, 256, 0, stream>>>(H0R, CTXP, d_in[2], d_in[4], AB0, AB1, d_out);
    // L3/L4: LSTM layer 0 (K=1664, 13 splits x 4 chunks)
    gemm_kernel<<<dim3(64, 13), 256, 0, stream>>>(H0R, AB0, 1664, 640, d_in[12], d_in[13], GS, 4);
    gate_kernel<<<256, 256, 0, stream>>>(H0R, GS, 13, d_in[14], d_in[2], d_in[3], d_out,
                                         O_H0, O_C0, 0, HCAT, 0, AB1);
    // L5/L6: LSTM layer 1 (K=2560, 16 splits x 5 chunks)
    gemm_kernel<<<dim3(64, 16), 256, 0, stream>>>(H0R, AB1, 2560, 1536, d_in[15], d_in[16], GS, 5);
    gate_kernel<<<256, 256, 0, stream>>>(H0R, GS, 16, d_in[17], d_in[4], d_in[5], d_out,
                                         O_H1, O_C1, 1024, HCAT, 1024, (u16*)nullptr);
    // L7: q = Hcat @ wq (8 k-splits, no atomics)
    qgemm_kernel<<<8, 256, 0, stream>>>(HCAT, BTWQ, QP);
    // L8: p = sigmoid(v . tanh(q + Mproj)) fused with w_new
    attn_kernel<<<dim3(16, 64), 256, 0, stream>>>(H0R, MPROJ, QP, d_in[20], d_in[21], d_in[1], d_out);
}

// Round 8
// 384.506 us; speedup vs baseline: 1.0749x; 1.0130x over previous
//
#include <hip/hip_runtime.h>
#include <hip/hip_bf16.h>
#include <stdint.h>

// Problem constants
#define B_  64
#define T_  1000
#define DC_ 512
#define DM_ 80
#define DP_ 128
#define DH_ 128
#define DA_ 128
#define DRN 1024
#define G4  4096

typedef __hip_bfloat16 bf16;
typedef unsigned short u16;
typedef unsigned int   u32;

// MFMA fragment types
typedef short bf8_t __attribute__((ext_vector_type(8)));
typedef float f4_t  __attribute__((ext_vector_type(4)));

// out element offsets: x_dec, ctx, w_new, h0n, c0n, h1n, c1n
#define O_XDEC 0
#define O_CTX  163840
#define O_WN   196608
#define O_H0   260608
#define O_C0   326144
#define O_H1   391680
#define O_C1   457216

__device__ __forceinline__ float b2f(bf16 v) { return __bfloat162float(v); }
__device__ __forceinline__ bf16  f2b(float v) { return __float2bfloat16(v); }
__device__ __forceinline__ u16   f2bu(float v) { return __builtin_bit_cast(u16, __float2bfloat16(v)); }

__device__ __forceinline__ float ldv(const float* p, size_t i) { return p[i]; }
__device__ __forceinline__ float ldv(const bf16*  p, size_t i) { return b2f(p[i]); }
__device__ __forceinline__ void  stv(float* p, size_t i, float v) { p[i] = v; }
__device__ __forceinline__ void  stv(bf16*  p, size_t i, float v) { p[i] = f2b(v); }

// load 8 consecutive elems as f32
template<typename T>
__device__ __forceinline__ void ld8f(const T* p, size_t i, float* o) {
    if constexpr (sizeof(T) == 2) {
        uint4 u = *(const uint4*)((const u16*)p + i);
        o[0] = __uint_as_float(u.x << 16); o[1] = __uint_as_float(u.x & 0xffff0000u);
        o[2] = __uint_as_float(u.y << 16); o[3] = __uint_as_float(u.y & 0xffff0000u);
        o[4] = __uint_as_float(u.z << 16); o[5] = __uint_as_float(u.z & 0xffff0000u);
        o[6] = __uint_as_float(u.w << 16); o[7] = __uint_as_float(u.w & 0xffff0000u);
    } else {
        float4 a = *(const float4*)(p + i);
        float4 b = *(const float4*)(p + i + 4);
        o[0]=a.x; o[1]=a.y; o[2]=a.z; o[3]=a.w; o[4]=b.x; o[5]=b.y; o[6]=b.z; o[7]=b.w;
    }
}
__device__ __forceinline__ void ld8f_bits(const u16* p, size_t i, float* o) {
    uint4 u = *(const uint4*)(p + i);
    o[0] = __uint_as_float(u.x << 16); o[1] = __uint_as_float(u.x & 0xffff0000u);
    o[2] = __uint_as_float(u.y << 16); o[3] = __uint_as_float(u.y & 0xffff0000u);
    o[4] = __uint_as_float(u.z << 16); o[5] = __uint_as_float(u.z & 0xffff0000u);
    o[6] = __uint_as_float(u.w << 16); o[7] = __uint_as_float(u.w & 0xffff0000u);
}

// ---------------- per-block dtype sniff (proven heuristic; wave-uniform) -----
__device__ __forceinline__ bool sniff_is_f32(const u32* h0raw) {
    int lane = threadIdx.x & 63;
    int c = 0;
    #pragma unroll
    for (int i = 0; i < 4; ++i) {
        u32 e = (h0raw[lane * 4 + i] >> 7) & 0xFF;
        c += (e >= 100 && e <= 126) ? 1 : 0;
    }
    #pragma unroll
    for (int s = 1; s < 64; s <<= 1) c += __shfl_xor(c, s);
    return c < 128;
}

// ---------------- Threefry-2x32 (bit-exact vs JAX — do not touch) ------------
__device__ __forceinline__ u32 rotl32(u32 v, int r) { return (v << r) | (v >> (32 - r)); }
__device__ __forceinline__ void threefry2x32(u32 k0, u32 k1, u32 x0, u32 x1, u32& y0, u32& y1) {
    u32 ks2 = k0 ^ k1 ^ 0x1BD11BDAu;
    x0 += k0; x1 += k1;
#define TF_R(r) { x0 += x1; x1 = rotl32(x1, r); x1 ^= x0; }
    TF_R(13) TF_R(15) TF_R(26) TF_R(6)
    x0 += k1; x1 += ks2 + 1u;
    TF_R(17) TF_R(29) TF_R(16) TF_R(24)
    x0 += ks2; x1 += k0 + 2u;
    TF_R(13) TF_R(15) TF_R(26) TF_R(6)
    x0 += k0; x1 += k1 + 3u;
    TF_R(17) TF_R(29) TF_R(16) TF_R(24)
    x0 += k1; x1 += ks2 + 4u;
    TF_R(13) TF_R(15) TF_R(26) TF_R(6)
    x0 += ks2; x1 += k0 + 5u;
#undef TF_R
    y0 = x0; y1 = x1;
}
__device__ __forceinline__ float dropout_mask(int which, int j) {
    u32 dk0, dk1, b1, b2;
    threefry2x32(0u, 42u, 0u, (u32)which, dk0, dk1);
    threefry2x32(dk0, dk1, 0u, (u32)j, b1, b2);
    u32 bits = b1 ^ b2;
    float u = __uint_as_float((bits >> 9) | 0x3f800000u) - 1.0f;
    return (u < 0.5f) ? 2.0f : 0.0f;
}

// ============== L0: prep = btprep-wm (blocks 0..31) + prenet (32..95) ========
template<typename T>
__device__ void prep_impl(const T* wm, u16* BTwm,
                          const T* x, const T* w1, const T* pb1, const T* w2, const T* pb2,
                          u16* Ab0, float* shbuf) {
    int bid = blockIdx.x, tid = threadIdx.x;
    if (bid < 32) {
        int gid = bid * 256 + tid;          // < 8192
        int L = gid & 63, kc = (gid >> 6) & 15, at = gid >> 10;
        u16* dst = BTwm + (size_t)gid * 8;
        int col = at * 16 + (L & 15);
        int krow = kc * 32 + (L >> 4) * 8;
        u16 v[8];
        #pragma unroll
        for (int j = 0; j < 8; ++j) v[j] = f2bu(ldv(wm, (size_t)(krow + j) * DA_ + col));
        uint4 pk;
        pk.x = v[0] | ((u32)v[1] << 16); pk.y = v[2] | ((u32)v[3] << 16);
        pk.z = v[4] | ((u32)v[5] << 16); pk.w = v[6] | ((u32)v[7] << 16);
        *(uint4*)dst = pk;
    } else {
        int b = bid - 32;
        float* xs = shbuf;            // [80]
        float* hs = shbuf + DM_;      // [128]
        if (tid < DM_) xs[tid] = ldv(x, (size_t)b * DM_ + tid);
        __syncthreads();
        if (tid < DH_) {
            float acc = ldv(pb1, tid);
            #pragma unroll 8
            for (int k = 0; k < DM_; ++k) acc = fmaf(xs[k], ldv(w1, (size_t)k * DH_ + tid), acc);
            acc = fmaxf(acc, 0.f) * dropout_mask(0, b * DH_ + tid);
            hs[tid] = acc;
        }
        __syncthreads();
        if (tid < DP_) {
            float acc2 = ldv(pb2, tid);
            #pragma unroll 8
            for (int k = 0; k < DH_; ++k) acc2 = fmaf(hs[k], ldv(w2, (size_t)k * DP_ + tid), acc2);
            acc2 = fmaxf(acc2, 0.f) * dropout_mask(1, b * DP_ + tid);
            Ab0[(size_t)b * 1664 + tid] = f2bu(acc2);
        }
    }
}
__global__ __launch_bounds__(256) void prep_kernel(const u32* h0r,
        const void* wm, u16* BTwm,
        const void* x, const void* w1, const void* pb1, const void* w2, const void* pb2,
        u16* Ab0) {
    __shared__ float shbuf[DM_ + DH_];
    if (sniff_is_f32(h0r))
        prep_impl<float>((const float*)wm, BTwm, (const float*)x,
                         (const float*)w1, (const float*)pb1, (const float*)w2, (const float*)pb2, Ab0, shbuf);
    else
        prep_impl<bf16>((const bf16*)wm, BTwm, (const bf16*)x,
                        (const bf16*)w1, (const bf16*)pb1, (const bf16*)w2, (const bf16*)pb2, Ab0, shbuf);
}

// ============== L1: fused ctx + Mproj, pipelined, per-wave reg B-frags =======
// grid (8, 64), 512 thr = 8 waves. Block = 128 t-rows (2 tiles x 2 c-phases =
// 4 steps, fully unrolled). Wave w owns at-tile w (16 B-frags = 64 VGPR,
// loaded once). ctx-FMA runs in the WRITE phase straight from the staged
// registers (f32 path: exact f32) -> compute phase is pure ds_read+MFMA.
// Staging prefetches step s+1 right after the write barrier.
template<typename T>
__device__ void ctxproj_impl(const T* mem, const T* w, const u16* BTwm,
                             float* CTXP, u16* Mproj, u16* Alds, float* shw) {
    int tid = threadIdx.x;
    int t0 = blockIdx.x * 128, b = blockIdx.y;
    if (tid < 128) shw[tid] = (t0 + tid < T_) ? ldv(w, (size_t)b * T_ + t0 + tid) : 0.f;
    int L = tid & 63;
    int m = L & 15, q16 = L >> 4;
    int wat = tid >> 6;                 // wave's at-tile (0..7)
    int rg = tid >> 5, cg = tid & 31;   // cacc reduce grouping (cols fixed per thread)

    // wave-persistent B-fragments for at-tile `wat` (static idx)
    bf8_t bw[16];
    #pragma unroll
    for (int kc = 0; kc < 16; ++kc)
        bw[kc] = *(const bf8_t*)(BTwm + ((size_t)(wat * 16 + kc) * 64 + L) * 8);

    f4_t acc[4];
    #pragma unroll
    for (int mt = 0; mt < 4; ++mt) acc[mt] = (f4_t){0.f, 0.f, 0.f, 0.f};
    float cacc[16] = {};
    uint4  stb[4];       // bf16 raw staging
    float4 stf[8];       // f32 raw staging (pairs)

#define LOADSTEP(S) do {                                                         \
        const int tt_ = (S) >> 1, ph_ = (S) & 1;                                 \
        _Pragma("unroll")                                                        \
        for (int rr = 0; rr < 4; ++rr) {                                         \
            int i = rr * 512 + tid;                                              \
            int row = i >> 5, c16 = i & 31;                                      \
            int t = t0 + tt_ * 64 + row;                                         \
            size_t base = (size_t)(b * T_ + ((t < T_) ? t : 0)) * DC_ + ph_ * 256 + c16 * 8; \
            if constexpr (sizeof(T) == 2) {                                      \
                stb[rr] = (t < T_) ? *(const uint4*)((const u16*)mem + base)     \
                                   : make_uint4(0u, 0u, 0u, 0u);                 \
            } else {                                                             \
                if (t < T_) { stf[2*rr]   = *(const float4*)(mem + base);        \
                              stf[2*rr+1] = *(const float4*)(mem + base + 4); }  \
                else { stf[2*rr] = make_float4(0.f,0.f,0.f,0.f);                 \
                       stf[2*rr+1] = make_float4(0.f,0.f,0.f,0.f); }             \
            }                                                                    \
        }                                                                        \
    } while (0)

    LOADSTEP(0);
    #pragma unroll
    for (int step = 0; step < 4; ++step) {
        const int tt = step >> 1, ph = step & 1;
        __syncthreads();                  // prior compute done reading Alds; (step0: shw ready)
        #pragma unroll
        for (int rr = 0; rr < 4; ++rr) {
            int i = rr * 512 + tid;
            int row = i >> 5, c16 = i & 31;
            float wvv = shw[tt * 64 + row];
            uint4 v;
            if constexpr (sizeof(T) == 2) {
                v = stb[rr];
                float f0 = __uint_as_float(v.x << 16), f1 = __uint_as_float(v.x & 0xffff0000u);
                float f2 = __uint_as_float(v.y << 16), f3 = __uint_as_float(v.y & 0xffff0000u);
                float f4 = __uint_as_float(v.z << 16), f5 = __uint_as_float(v.z & 0xffff0000u);
                float f6 = __uint_as_float(v.w << 16), f7 = __uint_as_float(v.w & 0xffff0000u);
                cacc[ph*8+0] = fmaf(wvv, f0, cacc[ph*8+0]); cacc[ph*8+1] = fmaf(wvv, f1, cacc[ph*8+1]);
                cacc[ph*8+2] = fmaf(wvv, f2, cacc[ph*8+2]); cacc[ph*8+3] = fmaf(wvv, f3, cacc[ph*8+3]);
                cacc[ph*8+4] = fmaf(wvv, f4, cacc[ph*8+4]); cacc[ph*8+5] = fmaf(wvv, f5, cacc[ph*8+5]);
                cacc[ph*8+6] = fmaf(wvv, f6, cacc[ph*8+6]); cacc[ph*8+7] = fmaf(wvv, f7, cacc[ph*8+7]);
            } else {
                float4 a = stf[2*rr], bb = stf[2*rr+1];
                cacc[ph*8+0] = fmaf(wvv, a.x,  cacc[ph*8+0]); cacc[ph*8+1] = fmaf(wvv, a.y,  cacc[ph*8+1]);
                cacc[ph*8+2] = fmaf(wvv, a.z,  cacc[ph*8+2]); cacc[ph*8+3] = fmaf(wvv, a.w,  cacc[ph*8+3]);
                cacc[ph*8+4] = fmaf(wvv, bb.x, cacc[ph*8+4]); cacc[ph*8+5] = fmaf(wvv, bb.y, cacc[ph*8+5]);
                cacc[ph*8+6] = fmaf(wvv, bb.z, cacc[ph*8+6]); cacc[ph*8+7] = fmaf(wvv, bb.w, cacc[ph*8+7]);
                v.x = (u32)f2bu(a.x)  | ((u32)f2bu(a.y)  << 16);
                v.y = (u32)f2bu(a.z)  | ((u32)f2bu(a.w)  << 16);
                v.z = (u32)f2bu(bb.x) | ((u32)f2bu(bb.y) << 16);
                v.w = (u32)f2bu(bb.z) | ((u32)f2bu(bb.w) << 16);
            }
            *(uint4*)(Alds + row * 264 + c16 * 8) = v;
        }
        __syncthreads();
        if (step == 0) LOADSTEP(1);       // prefetch: loads span the compute below
        else if (step == 1) LOADSTEP(2);
        else if (step == 2) LOADSTEP(3);
        // MFMA: wave's at-tile x all 4 m-tiles; af from LDS, bfrag from regs
        #pragma unroll
        for (int kcl = 0; kcl < 8; ++kcl) {
            const int kc = ph * 8 + kcl;
            #pragma unroll
            for (int mt = 0; mt < 4; ++mt) {
                bf8_t af = *(const bf8_t*)(Alds + (mt * 16 + m) * 264 + kcl * 32 + q16 * 8);
                acc[mt] = __builtin_amdgcn_mfma_f32_16x16x32_bf16(af, bw[kc], acc[mt], 0, 0, 0);
            }
        }
        // tile complete (ph==1): store Mproj (proven C/D layout), reset acc
        if (ph == 1) {
            #pragma unroll
            for (int mt = 0; mt < 4; ++mt) {
                #pragma unroll
                for (int r = 0; r < 4; ++r) {
                    int trow = t0 + tt * 64 + mt * 16 + q16 * 4 + r;
                    if (trow < T_)
                        Mproj[(size_t)(b * T_ + trow) * DA_ + wat * 16 + m] = f2bu(acc[mt][r]);
                }
                acc[mt] = (f4_t){0.f, 0.f, 0.f, 0.f};
            }
        }
    }
#undef LOADSTEP
    // ctx partial reduce through reused Alds -> CTXP[chunk][b][c]
    __syncthreads();
    float* part = (float*)Alds;   // 16 groups x 512 cols = 32 KB (fits 33 KB)
    #pragma unroll
    for (int ph = 0; ph < 2; ++ph)
        #pragma unroll
        for (int j = 0; j < 8; ++j)
            part[rg * 512 + ph * 256 + cg * 8 + j] = cacc[ph * 8 + j];
    __syncthreads();
    int c = tid;                  // 0..511
    float s = 0.f;
    #pragma unroll
    for (int gg = 0; gg < 16; ++gg) s += part[gg * 512 + c];
    CTXP[((size_t)blockIdx.x * 64 + b) * DC_ + c] = s;
}
// separate kernels so f32-path register pressure can't inflate the bf16 path
__global__ __launch_bounds__(512, 1) void ctxproj_bf16_kernel(const u32* h0r,
        const void* mem, const void* w, const u16* BTwm, float* CTXP, u16* Mproj) {
    __shared__ __align__(16) u16 Alds[64 * 264];
    __shared__ float shw[128];
    if (sniff_is_f32(h0r)) return;
    ctxproj_impl<bf16>((const bf16*)mem, (const bf16*)w, BTwm, CTXP, Mproj, Alds, shw);
}
__global__ __launch_bounds__(512, 1) void ctxproj_f32_kernel(const u32* h0r,
        const void* mem, const void* w, const u16* BTwm, float* CTXP, u16* Mproj) {
    __shared__ __align__(16) u16 Alds[64 * 264];
    __shared__ float shw[128];
    if (!sniff_is_f32(h0r)) return;
    ctxproj_impl<float>((const float*)mem, (const float*)w, BTwm, CTXP, Mproj, Alds, shw);
}

// ============== L2: pack0 = ctx reduce + A-buffer packing + QP zero ==========
template<typename T>
__device__ void pack0_impl(const float* CTXP, const T* h0p, const T* h1p,
                           u16* Ab0, u16* Ab1, float* QPf, T* out) {
    int b = blockIdx.x, tid = threadIdx.x;
    T* ctxout = out + O_CTX;
    T* xdec = out + O_XDEC;
    if (tid < 128) QPf[(size_t)b * DA_ + tid] = 0.f;
    for (int c = tid; c < DC_; c += 256) {
        float s = 0.f;
        #pragma unroll
        for (int t = 0; t < 8; ++t) s += CTXP[((size_t)t * 64 + b) * DC_ + c];
        u16 bv = f2bu(s);
        Ab0[(size_t)b * 1664 + 128 + c] = bv;
        Ab1[(size_t)b * 2560 + 1024 + c] = bv;
        stv(ctxout, (size_t)b * DC_ + c, s);
        stv(xdec, (size_t)b * 2560 + 2048 + c, 0.f);
    }
    for (int u = tid; u < DRN; u += 256) {
        Ab0[(size_t)b * 1664 + 640 + u]  = f2bu(ldv(h0p, (size_t)b * DRN + u));
        Ab1[(size_t)b * 2560 + 1536 + u] = f2bu(ldv(h1p, (size_t)b * DRN + u));
    }
}
__global__ __launch_bounds__(256) void pack0_kernel(const u32* h0r, const float* CTXP,
        const void* h0p, const void* h1p, u16* Ab0, u16* Ab1, float* QPf, void* out) {
    if (sniff_is_f32(h0r))
        pack0_impl<float>(CTXP, (const float*)h0p, (const float*)h1p, Ab0, Ab1, QPf, (float*)out);
    else
        pack0_impl<bf16>(CTXP, (const bf16*)h0p, (const bf16*)h1p, Ab0, Ab1, QPf, (bf16*)out);
}

// ============== L3/L5: LSTM gate GEMM (BK=64, T14 reg-prefetch) ==============
// C[64][4096] = A[64][K]@[Wih;Whh]; grid (64 n-tiles, NSPLIT), 256 thr.
// Per chunk: 64 k-rows. A-stage: thread (tid>>2, (tid&3)*16). W-stage same.
template<typename T>
__device__ void gemm_impl(const u16* Abuf, int K, int L12, const T* Wih, const T* Whh,
                          float* Gs, int nchunks, float (*As)[66], float (*Ws)[64]) {
    int tid = threadIdx.x;
    int n0b = blockIdx.x * 64;
    int kbase = blockIdx.y * (nchunks * 64);
    int cx = tid & 15, ry = tid >> 4;
    int b0 = ry * 4, n0 = cx * 4;
    int a_bb = tid >> 2, a_k16 = (tid & 3) * 16;
    int w_k  = tid >> 2, w_n16 = (tid & 3) * 16;
    float acc[4][4] = {};
    float va[16], vw[16];
#define GLOAD(CH) do {                                                          \
        int k0 = kbase + (CH) * 64;                                             \
        ld8f_bits(Abuf, (size_t)a_bb * K + k0 + a_k16, va);                     \
        ld8f_bits(Abuf, (size_t)a_bb * K + k0 + a_k16 + 8, va + 8);             \
        int kg = k0 + w_k;                                                      \
        const T* wr = (kg < L12) ? (Wih + (size_t)kg * G4) : (Whh + (size_t)(kg - L12) * G4); \
        ld8f(wr, n0b + w_n16, vw);                                              \
        ld8f(wr, n0b + w_n16 + 8, vw + 8);                                      \
    } while (0)
    GLOAD(0);
    for (int ch = 0; ch < nchunks; ++ch) {
        __syncthreads();                        // prev compute done reading LDS
        #pragma unroll
        for (int j = 0; j < 16; ++j) As[a_bb][a_k16 + j] = va[j];
        #pragma unroll
        for (int j = 0; j < 16; ++j) Ws[w_k][w_n16 + j] = vw[j];
        __syncthreads();
        if (ch + 1 < nchunks) GLOAD(ch + 1);    // prefetch spans compute
        #pragma unroll
        for (int kk = 0; kk < 64; kk += 2) {
            float2 av[4];
            #pragma unroll
            for (int r = 0; r < 4; ++r) av[r] = *(const float2*)&As[b0 + r][kk];
            float4 w0 = *(const float4*)&Ws[kk][n0];
            float4 w1 = *(const float4*)&Ws[kk + 1][n0];
            #pragma unroll
            for (int r = 0; r < 4; ++r) {
                acc[r][0] = fmaf(av[r].x, w0.x, acc[r][0]); acc[r][0] = fmaf(av[r].y, w1.x, acc[r][0]);
                acc[r][1] = fmaf(av[r].x, w0.y, acc[r][1]); acc[r][1] = fmaf(av[r].y, w1.y, acc[r][1]);
                acc[r][2] = fmaf(av[r].x, w0.z, acc[r][2]); acc[r][2] = fmaf(av[r].y, w1.z, acc[r][2]);
                acc[r][3] = fmaf(av[r].x, w0.w, acc[r][3]); acc[r][3] = fmaf(av[r].y, w1.w, acc[r][3]);
            }
        }
    }
#undef GLOAD
    float* outp = Gs + (size_t)blockIdx.y * (64 * G4);
    #pragma unroll
    for (int r = 0; r < 4; ++r)
        *(float4*)&outp[(size_t)(b0 + r) * G4 + n0b + n0] =
            make_float4(acc[r][0], acc[r][1], acc[r][2], acc[r][3]);
}
__global__ __launch_bounds__(256) void gemm_kernel(const u32* h0r, const u16* Abuf,
        int K, int L12, const void* Wih, const void* Whh, float* Gs, int nchunks) {
    __shared__ float As[64][66];
    __shared__ float Ws[64][64];
    if (sniff_is_f32(h0r))
        gemm_impl<float>(Abuf, K, L12, (const float*)Wih, (const float*)Whh, Gs, nchunks, As, Ws);
    else
        gemm_impl<bf16>(Abuf, K, L12, (const bf16*)Wih, (const bf16*)Whh, Gs, nchunks, As, Ws);
}

// ============== L4/L6: split-reduce + gates + zoneout + fused q-partial ======
// grid 256 blocks x 256 thr; block covers b = blockIdx>>2, u0 = (blockIdx&3)*256.
// After gates: LDS-reduce sum_u ho[u]*wq[qrow0+u0+u][a] -> one atomicAdd per (b,a).
template<typename T>
__device__ void gate_impl(const float* Gs, int nsplit, const T* bias, const T* hprev,
                          const T* cprev, const T* wq, int qrow0, float* QPf,
                          T* out, int ho_off, int co_off, int xoff, u16* Ab1,
                          float* hos, float* sarr) {
    int tid = threadIdx.x;
    int idx = blockIdx.x * 256 + tid;             // [0, 65536)
    int b = idx >> 10, u = idx & 1023;
    int u0 = (blockIdx.x & 3) * 256;
    float gi = ldv(bias, u);
    float gf = ldv(bias, 1024 + u);
    float gg = ldv(bias, 2048 + u);
    float go = ldv(bias, 3072 + u);
    for (int s = 0; s < nsplit; ++s) {
        const float* g = Gs + (size_t)s * (64 * G4) + (size_t)b * G4;
        gi += g[u]; gf += g[1024 + u]; gg += g[2048 + u]; go += g[3072 + u];
    }
    float c = ldv(cprev, idx), h = ldv(hprev, idx);
    float si = 1.f / (1.f + expf(-gi));
    float sf = 1.f / (1.f + expf(-gf));
    float so = 1.f / (1.f + expf(-go));
    float cn = sf * c + si * tanhf(gg);
    float hn = so * tanhf(cn);
    float ho = 0.9f * hn + 0.1f * h;
    float co = 0.9f * cn + 0.1f * c;
    stv(out + ho_off, idx, ho);
    stv(out + co_off, idx, co);
    stv(out + O_XDEC, (size_t)b * 2560 + xoff + u, ho);
    if (Ab1 != nullptr) Ab1[(size_t)b * 2560 + u] = f2bu(ho);
    // fused q-partial: q[b,a] += sum_u ho[u] * wq[qrow0+u0+u][a]
    hos[tid] = ho;
    __syncthreads();
    int a = tid & 127, half = tid >> 7;
    float s = 0.f;
    #pragma unroll 8
    for (int j = 0; j < 128; ++j)
        s = fmaf(hos[half * 128 + j], ldv(wq, (size_t)(qrow0 + u0 + half * 128 + j) * DA_ + a), s);
    sarr[tid] = s;
    __syncthreads();
    if (tid < 128) atomicAdd(&QPf[(size_t)b * DA_ + tid], sarr[tid] + sarr[128 + tid]);
}
__global__ __launch_bounds__(256) void gate_kernel(const u32* h0r, const float* Gs, int nsplit,
        const void* bias, const void* hprev, const void* cprev, const void* wq, int qrow0,
        float* QPf, void* out, int ho_off, int co_off, int xoff, u16* Ab1) {
    __shared__ float hos[256];
    __shared__ float sarr[256];
    if (sniff_is_f32(h0r))
        gate_impl<float>(Gs, nsplit, (const float*)bias, (const float*)hprev, (const float*)cprev,
                         (const float*)wq, qrow0, QPf, (float*)out, ho_off, co_off, xoff, Ab1, hos, sarr);
    else
        gate_impl<bf16>(Gs, nsplit, (const bf16*)bias, (const bf16*)hprev, (const bf16*)cprev,
                        (const bf16*)wq, qrow0, QPf, (bf16*)out, ho_off, co_off, xoff, Ab1, hos, sarr);
}

// ============== L8: attention epilogue (tanh-dot-sigmoid) + fused wnew =======
template<typename T>
__device__ void attn_impl(const u16* Mproj, const float* QPf, const T* ab, const T* av,
                          const T* w, T* out, float* qa, float* avl, float* psh) {
    int tid = threadIdx.x;
    int t0 = blockIdx.x * 64, b = blockIdx.y;
    T* wout = out + O_WN;
    if (tid < DA_) {
        qa[tid]  = ldv(ab, tid) + QPf[(size_t)b * DA_ + tid];
        avl[tid] = ldv(av, tid);
    }
    __syncthreads();
    int quad = tid & 3, r = tid >> 2;   // 4 threads per row, 32 a each
    #pragma unroll
    for (int rbase = 0; rbase < 2; ++rbase) {
        int rrow = (rbase == 0) ? r : 64;          // row 64 handled by r==0 quads
        bool act = (rbase == 0) || (r == 0);
        int t = t0 - 1 + rrow;
        float e = 0.f;
        if (act && t >= 0 && t < T_) {
            #pragma unroll
            for (int a8 = 0; a8 < 4; ++a8) {
                float v[8];
                ld8f_bits(Mproj, (size_t)(b * T_ + t) * DA_ + quad * 32 + a8 * 8, v);
                #pragma unroll
                for (int j = 0; j < 8; ++j) {
                    int a = quad * 32 + a8 * 8 + j;
                    e = fmaf(avl[a], tanhf(qa[a] + v[j]), e);
                }
            }
        }
        e += __shfl_xor(e, 1);
        e += __shfl_xor(e, 2);
        if (act && quad == 0 && t >= 0 && t < T_) psh[rrow] = 1.f / (1.f + expf(-e));
    }
    __syncthreads();
    if (tid < 64) {
        int t = t0 + tid;
        if (t < T_) {
            float val = ldv(w, (size_t)b * T_ + t) * psh[tid + 1];
            if (t > 0) val = fmaf(ldv(w, (size_t)b * T_ + t - 1), 1.f - psh[tid], val);
            stv(wout, (size_t)b * T_ + t, val);
        }
    }
}
__global__ __launch_bounds__(256) void attn_kernel(const u32* h0r, const u16* Mproj,
        const float* QPf, const void* ab, const void* av, const void* w, void* out) {
    __shared__ float qa[DA_];
    __shared__ float avl[DA_];
    __shared__ float psh[66];
    if (sniff_is_f32(h0r))
        attn_impl<float>(Mproj, QPf, (const float*)ab, (const float*)av, (const float*)w,
                         (float*)out, qa, avl, psh);
    else
        attn_impl<bf16>(Mproj, QPf, (const bf16*)ab, (const bf16*)av, (const bf16*)w,
                        (bf16*)out, qa, avl, psh);
}

// ---------------- launch -----------------------------------------------------
extern "C" void kernel_launch(void* const* d_in, const int* in_sizes, int n_in,
                              void* d_out, int out_size, void* d_ws, size_t ws_size,
                              hipStream_t stream) {
    (void)in_sizes; (void)n_in; (void)out_size; (void)ws_size;

    // workspace layout (f32 units). Total ~37 MiB.
    float* wsf   = (float*)d_ws;
    float* GS    = wsf;                        // 16 x 262144 (per-split gate buffers)
    float* CTXP  = wsf + 4194304;              // 8 x 64 x 512 ctx partials
    float* QPf   = wsf + 4718592;              // 64 x 128 accumulated q
    u16*   MPROJ = (u16*)(wsf + 4784128);      // 64 x 1000 x 128 bf16
    u16*   AB0   = (u16*)(wsf + 8880128);      // 64 x 1664 bf16
    u16*   AB1   = (u16*)(wsf + 8933376);      // 64 x 2560 bf16
    u16*   BTWM  = (u16*)(wsf + 9080832);      // 65536 bf16

    const u32* H0R = (const u32*)d_in[2];

    // L0: B-fragment prep (wm) + prenet -> AB0[:,0:128]
    prep_kernel<<<96, 256, 0, stream>>>(H0R, d_in[19], BTWM,
                                        d_in[0], d_in[8], d_in[9], d_in[10], d_in[11], AB0);
    // L1: fused ctx + Mproj, single pass over memory (dtype-split kernels)
    ctxproj_bf16_kernel<<<dim3(8, 64), 512, 0, stream>>>(H0R, d_in[6], d_in[1], BTWM, CTXP, MPROJ);
    ctxproj_f32_kernel <<<dim3(8, 64), 512, 0, stream>>>(H0R, d_in[6], d_in[1], BTWM, CTXP, MPROJ);
    // L2: ctx reduce + A-buffer packing + QP zero + xdec tail zeros
    pack0_kernel<<<64, 256, 0, stream>>>(H0R, CTXP, d_in[2], d_in[4], AB0, AB1, QPf, d_out);
    // L3/L4: LSTM layer 0 (K=1664, 13 splits x 2 chunks of 64)
    gemm_kernel<<<dim3(64, 13), 256, 0, stream>>>(H0R, AB0, 1664, 640, d_in[12], d_in[13], GS, 2);
    gate_kernel<<<256, 256, 0, stream>>>(H0R, GS, 13, d_in[14], d_in[2], d_in[3],
                                         d_in[18], 0, QPf, d_out, O_H0, O_C0, 0, AB1);
    // L5/L6: LSTM layer 1 (K=2560, 10 splits x 4 chunks of 64)
    gemm_kernel<<<dim3(64, 10), 256, 0, stream>>>(H0R, AB1, 2560, 1536, d_in[15], d_in[16], GS, 4);
    gate_kernel<<<256, 256, 0, stream>>>(H0R, GS, 10, d_in[17], d_in[4], d_in[5],
                                         d_in[18], 1024, QPf, d_out, O_H1, O_C1, 1024, (u16*)nullptr);
    // L8: p = sigmoid(v . tanh(q + Mproj)) fused with w_new
    attn_kernel<<<dim3(16, 64), 256, 0, stream>>>(H0R, MPROJ, QPf, d_in[20], d_in[21], d_in[1], d_out);
}